// Round 2
// baseline (2012.083 us; speedup 1.0000x reference)
//
#include <hip/hip_runtime.h>
#include <hip/hip_bf16.h>

// Problem constants
#define NB 64      // batch
#define NT_ 64     // time steps
#define NS 512     // source positions
#define NI 512     // input dim
#define NH 512     // hidden
#define G4 2048    // 4*H
#define H2 1024    // 2*H
#define BT (NB*NT_)

typedef __attribute__((ext_vector_type(8))) short short8;   // 8 bf16 (4 VGPRs)
typedef __attribute__((ext_vector_type(4))) float f32x4;    // MFMA accumulator

__device__ __forceinline__ short f2bs(float f) {
    __hip_bfloat16 h = __float2bfloat16(f);
    return *reinterpret_cast<short*>(&h);
}
__device__ __forceinline__ float bs2f(short s) {
    unsigned int u = ((unsigned int)(unsigned short)s) << 16;
    union { unsigned int u; float f; } c; c.u = u; return c.f;
}
__device__ __forceinline__ short8 ld8b(const __hip_bfloat16* p) {
    return *reinterpret_cast<const short8*>(p);
}
// load 8 fp32, produce hi & lo bf16 fragments (x ~= hi + lo, rel err ~2^-16)
__device__ __forceinline__ void ld8f2(const float* p, short8& hi, short8& lo) {
    float4 a = *reinterpret_cast<const float4*>(p);
    float4 b = *reinterpret_cast<const float4*>(p + 4);
    float v[8] = {a.x,a.y,a.z,a.w,b.x,b.y,b.z,b.w};
    #pragma unroll
    for (int i = 0; i < 8; i++) {
        short h = f2bs(v[i]);
        hi[i] = h;
        lo[i] = f2bs(v[i] - bs2f(h));
    }
}
__device__ __forceinline__ float sigm(float x){ return 1.f/(1.f + __expf(-x)); }

// ---------------- conversions ----------------
__global__ __launch_bounds__(256) void conv_split(const float* __restrict__ s,
                                                  __hip_bfloat16* __restrict__ hi,
                                                  __hip_bfloat16* __restrict__ lo, int n) {
    for (int i = blockIdx.x*256 + threadIdx.x; i < n; i += gridDim.x*256) {
        float x = s[i];
        __hip_bfloat16 h = __float2bfloat16(x);
        hi[i] = h;
        lo[i] = __float2bfloat16(x - __bfloat162float(h));
    }
}
__global__ __launch_bounds__(256) void copy_f(const float* __restrict__ s,
                                              float* __restrict__ d, int n) {
    for (int i = blockIdx.x*256 + threadIdx.x; i < n; i += gridDim.x*256) d[i] = s[i];
}

// ctxT[b][h][s] = bf16(ctx[s][b][h])  — for the wc GEMM (dot over s)
__global__ __launch_bounds__(256) void transpose_ctx(const float* __restrict__ ctx,
                                                     __hip_bfloat16* __restrict__ ctxT) {
    __shared__ float tile[64][65];
    int s0 = blockIdx.x*64, h0 = blockIdx.y*64, b = blockIdx.z;
    int tx = threadIdx.x & 63, ty = threadIdx.x >> 6;
    for (int i = 0; i < 16; i++) {
        int s = i*4 + ty;
        tile[s][tx] = ctx[(size_t)(s0+s)*NB*NH + (size_t)b*NH + h0 + tx];
    }
    __syncthreads();
    for (int i = 0; i < 16; i++) {
        int h = i*4 + ty;
        ctxT[(size_t)b*NH*NS + (size_t)(h0+h)*NS + s0 + tx] = __float2bfloat16(tile[tx][h]);
    }
}

// ---------------- XW = input @ W_ih^T + b_ih + b_hh  (M=4096,N=2048,K=512) ----------------
// split-precision: A on-the-fly hi/lo from fp32, B pre-split hi/lo
__global__ __launch_bounds__(256) void gemm_xw(const float* __restrict__ X,
                                               const __hip_bfloat16* __restrict__ Wh,
                                               const __hip_bfloat16* __restrict__ Wl,
                                               const float* __restrict__ b_ih,
                                               const float* __restrict__ b_hh,
                                               float* __restrict__ XW) {
    int wid = blockIdx.x*4 + (threadIdx.x>>6);
    int lane = threadIdx.x & 63;
    int m0 = (wid >> 5) * 64;
    int n0 = (wid & 31) * 64;
    int fr = lane & 15, fq = lane >> 4;
    f32x4 acc[4][4] = {};
    for (int kk = 0; kk < NI; kk += 32) {
        short8 ah[4], al[4], bh[4], bl[4];
        #pragma unroll
        for (int i = 0; i < 4; i++) ld8f2(X + (size_t)(m0+i*16+fr)*NI + kk + fq*8, ah[i], al[i]);
        #pragma unroll
        for (int j = 0; j < 4; j++) {
            bh[j] = ld8b(Wh + (size_t)(n0+j*16+fr)*NI + kk + fq*8);
            bl[j] = ld8b(Wl + (size_t)(n0+j*16+fr)*NI + kk + fq*8);
        }
        #pragma unroll
        for (int i = 0; i < 4; i++)
            #pragma unroll
            for (int j = 0; j < 4; j++) {
                acc[i][j] = __builtin_amdgcn_mfma_f32_16x16x32_bf16(ah[i], bh[j], acc[i][j], 0,0,0);
                acc[i][j] = __builtin_amdgcn_mfma_f32_16x16x32_bf16(ah[i], bl[j], acc[i][j], 0,0,0);
                acc[i][j] = __builtin_amdgcn_mfma_f32_16x16x32_bf16(al[i], bh[j], acc[i][j], 0,0,0);
            }
    }
    #pragma unroll
    for (int i = 0; i < 4; i++)
      #pragma unroll
      for (int j = 0; j < 4; j++)
        #pragma unroll
        for (int r = 0; r < 4; r++) {
            int m = m0 + i*16 + fq*4 + r;
            int n = n0 + j*16 + fr;
            XW[(size_t)m*G4 + n] = acc[i][j][r] + b_ih[n] + b_hh[n];
        }
}

// ---------------- one recurrence step ----------------
// gates = XW[:,t,:] + h@W_hh^T (split-precision); LSTM cell; ht -> Hf fp32
// grid = 16 blocks (each owns 32 cell columns), 4 waves = 4 gate groups (i,f,g,o)
__global__ __launch_bounds__(256) void lstm_step(const float* __restrict__ hprev, int lda,
                                                 const __hip_bfloat16* __restrict__ Wh,
                                                 const __hip_bfloat16* __restrict__ Wl,
                                                 const float* __restrict__ XW,
                                                 float* __restrict__ c_st,
                                                 float* __restrict__ Hf,
                                                 float* __restrict__ hTo, float* __restrict__ cTo,
                                                 int t) {
    __shared__ float gl[4][64][33];
    int w = threadIdx.x >> 6, lane = threadIdx.x & 63;
    int bi = blockIdx.x;
    int fr = lane & 15, fq = lane >> 4;
    int g0 = w*NH + bi*32;              // gate column base for this wave
    f32x4 acc[4][2] = {};
    for (int kk = 0; kk < NH; kk += 32) {
        short8 ah[4], al[4], bh[2], bl[2];
        #pragma unroll
        for (int i = 0; i < 4; i++) ld8f2(hprev + (size_t)(i*16+fr)*lda + kk + fq*8, ah[i], al[i]);
        #pragma unroll
        for (int j = 0; j < 2; j++) {
            bh[j] = ld8b(Wh + (size_t)(g0+j*16+fr)*NH + kk + fq*8);
            bl[j] = ld8b(Wl + (size_t)(g0+j*16+fr)*NH + kk + fq*8);
        }
        #pragma unroll
        for (int i = 0; i < 4; i++)
            #pragma unroll
            for (int j = 0; j < 2; j++) {
                acc[i][j] = __builtin_amdgcn_mfma_f32_16x16x32_bf16(ah[i], bh[j], acc[i][j], 0,0,0);
                acc[i][j] = __builtin_amdgcn_mfma_f32_16x16x32_bf16(ah[i], bl[j], acc[i][j], 0,0,0);
                acc[i][j] = __builtin_amdgcn_mfma_f32_16x16x32_bf16(al[i], bh[j], acc[i][j], 0,0,0);
            }
    }
    #pragma unroll
    for (int i = 0; i < 4; i++)
      #pragma unroll
      for (int j = 0; j < 2; j++)
        #pragma unroll
        for (int r = 0; r < 4; r++) {
            int b  = i*16 + fq*4 + r;
            int jl = j*16 + fr;
            gl[w][b][jl] = acc[i][j][r] + XW[((size_t)b*NT_ + t)*G4 + g0 + jl];
        }
    __syncthreads();
    // cell elementwise: 64 b x 32 j per block, 8 cells/thread
    int b  = threadIdx.x >> 2;
    int j0 = (threadIdx.x & 3) * 8;
    #pragma unroll
    for (int u = 0; u < 8; u++) {
        int jl = j0 + u;
        float gi = gl[0][b][jl], gf = gl[1][b][jl], gg = gl[2][b][jl], go = gl[3][b][jl];
        int cidx = b*NH + bi*32 + jl;
        float c  = c_st[cidx];
        float ct = sigm(gf)*c + sigm(gi)*tanhf(gg);
        float ht = sigm(go)*tanhf(ct);
        c_st[cidx] = ct;
        Hf[((size_t)b*NT_ + t)*NH + bi*32 + jl] = ht;
        hTo[cidx] = ht;   // final step's values remain as hT
        cTo[cidx] = ct;   // ... and cT
    }
}

// ---------------- scores[b,t,s] = Hf[b,t,:] . ctx[s,b,:]  (per-b M=64,N=512,K=512) ----------------
// both operands fp32, split on the fly
__global__ __launch_bounds__(256) void gemm_scores(const float* __restrict__ Hf,
                                                   const float* __restrict__ ctx,
                                                   float* __restrict__ scores) {
    int wid = blockIdx.x*4 + (threadIdx.x>>6);
    int lane = threadIdx.x & 63;
    int b  = wid >> 3;
    int n0 = (wid & 7) * 64;
    int fr = lane & 15, fq = lane >> 4;
    const float* Ab = Hf + (size_t)b*NT_*NH;
    const float* Bb = ctx + (size_t)b*NH;
    f32x4 acc[4][4] = {};
    for (int kk = 0; kk < NH; kk += 32) {
        short8 ah[4], al[4], bh[4], bl[4];
        #pragma unroll
        for (int i = 0; i < 4; i++) ld8f2(Ab + (size_t)(i*16+fr)*NH + kk + fq*8, ah[i], al[i]);
        #pragma unroll
        for (int j = 0; j < 4; j++) ld8f2(Bb + (size_t)(n0+j*16+fr)*NB*NH + kk + fq*8, bh[j], bl[j]);
        #pragma unroll
        for (int i = 0; i < 4; i++)
            #pragma unroll
            for (int j = 0; j < 4; j++) {
                acc[i][j] = __builtin_amdgcn_mfma_f32_16x16x32_bf16(ah[i], bh[j], acc[i][j], 0,0,0);
                acc[i][j] = __builtin_amdgcn_mfma_f32_16x16x32_bf16(ah[i], bl[j], acc[i][j], 0,0,0);
                acc[i][j] = __builtin_amdgcn_mfma_f32_16x16x32_bf16(al[i], bh[j], acc[i][j], 0,0,0);
            }
    }
    #pragma unroll
    for (int i = 0; i < 4; i++)
      #pragma unroll
      for (int j = 0; j < 4; j++)
        #pragma unroll
        for (int r = 0; r < 4; r++) {
            int t = i*16 + fq*4 + r;
            int s = n0 + j*16 + fr;
            scores[((size_t)b*NT_ + t)*NS + s] = acc[i][j][r];
        }
}

// ---------------- row softmax over S, output attn hi/lo bf16 ----------------
__global__ __launch_bounds__(256) void softmax_rows(const float* __restrict__ scores,
                                                    __hip_bfloat16* __restrict__ ah,
                                                    __hip_bfloat16* __restrict__ al) {
    int row = blockIdx.x*4 + (threadIdx.x>>6);
    int lane = threadIdx.x & 63;
    const float* r = scores + (size_t)row*NS;
    float v[8], mx = -1e30f;
    #pragma unroll
    for (int i = 0; i < 8; i++) { v[i] = r[lane + i*64]; mx = fmaxf(mx, v[i]); }
    #pragma unroll
    for (int off = 32; off; off >>= 1) mx = fmaxf(mx, __shfl_xor(mx, off));
    float sum = 0.f;
    #pragma unroll
    for (int i = 0; i < 8; i++) { v[i] = __expf(v[i]-mx); sum += v[i]; }
    #pragma unroll
    for (int off = 32; off; off >>= 1) sum += __shfl_xor(sum, off);
    float inv = 1.f/sum;
    #pragma unroll
    for (int i = 0; i < 8; i++) {
        float a = v[i]*inv;
        __hip_bfloat16 h = __float2bfloat16(a);
        ah[(size_t)row*NS + lane + i*64] = h;
        al[(size_t)row*NS + lane + i*64] = __float2bfloat16(a - __bfloat162float(h));
    }
}

// ---------------- Wc[b,t,h] = sum_s attn[b,t,s]*ctxT[b,h,s]  (fp32 out) ----------------
__global__ __launch_bounds__(256) void gemm_wc(const __hip_bfloat16* __restrict__ Ah,
                                               const __hip_bfloat16* __restrict__ Al,
                                               const __hip_bfloat16* __restrict__ ctxT,
                                               float* __restrict__ Wc) {
    int wid = blockIdx.x*4 + (threadIdx.x>>6);
    int lane = threadIdx.x & 63;
    int b  = wid >> 3;
    int n0 = (wid & 7) * 64;
    int fr = lane & 15, fq = lane >> 4;
    const __hip_bfloat16* Abh = Ah + (size_t)b*NT_*NS;
    const __hip_bfloat16* Abl = Al + (size_t)b*NT_*NS;
    const __hip_bfloat16* Bb  = ctxT + (size_t)b*NH*NS;
    f32x4 acc[4][4] = {};
    for (int kk = 0; kk < NS; kk += 32) {
        short8 ah[4], al[4], bb[4];
        #pragma unroll
        for (int i = 0; i < 4; i++) {
            ah[i] = ld8b(Abh + (size_t)(i*16+fr)*NS + kk + fq*8);
            al[i] = ld8b(Abl + (size_t)(i*16+fr)*NS + kk + fq*8);
        }
        #pragma unroll
        for (int j = 0; j < 4; j++) bb[j] = ld8b(Bb + (size_t)(n0+j*16+fr)*NS + kk + fq*8);
        #pragma unroll
        for (int i = 0; i < 4; i++)
            #pragma unroll
            for (int j = 0; j < 4; j++) {
                acc[i][j] = __builtin_amdgcn_mfma_f32_16x16x32_bf16(ah[i], bb[j], acc[i][j], 0,0,0);
                acc[i][j] = __builtin_amdgcn_mfma_f32_16x16x32_bf16(al[i], bb[j], acc[i][j], 0,0,0);
            }
    }
    #pragma unroll
    for (int i = 0; i < 4; i++)
      #pragma unroll
      for (int j = 0; j < 4; j++)
        #pragma unroll
        for (int r = 0; r < 4; r++) {
            int t = i*16 + fq*4 + r;
            int h = n0 + j*16 + fr;
            Wc[((size_t)b*NT_ + t)*NH + h] = acc[i][j][r];
        }
}

// ---------------- out = tanh([Wc|Hf] @ W_out^T)  (M=4096,N=512,K=1024) ----------------
__global__ __launch_bounds__(256) void gemm_out(const float* __restrict__ Wc,
                                                const float* __restrict__ Hf,
                                                const __hip_bfloat16* __restrict__ Wh,
                                                const __hip_bfloat16* __restrict__ Wl,
                                                float* __restrict__ out) {
    int wid = blockIdx.x*4 + (threadIdx.x>>6);
    int lane = threadIdx.x & 63;
    int m0 = (wid >> 3) * 64;
    int n0 = (wid & 7) * 64;
    int fr = lane & 15, fq = lane >> 4;
    f32x4 acc[4][4] = {};
    #pragma unroll 1
    for (int half = 0; half < 2; half++) {
        const float* Am = half ? Hf : Wc;
        int koff = half ? NH : 0;
        for (int kk = 0; kk < NH; kk += 32) {
            short8 ah[4], al[4], bh[4], bl[4];
            #pragma unroll
            for (int i = 0; i < 4; i++) ld8f2(Am + (size_t)(m0+i*16+fr)*NH + kk + fq*8, ah[i], al[i]);
            #pragma unroll
            for (int j = 0; j < 4; j++) {
                bh[j] = ld8b(Wh + (size_t)(n0+j*16+fr)*H2 + koff + kk + fq*8);
                bl[j] = ld8b(Wl + (size_t)(n0+j*16+fr)*H2 + koff + kk + fq*8);
            }
            #pragma unroll
            for (int i = 0; i < 4; i++)
                #pragma unroll
                for (int j = 0; j < 4; j++) {
                    acc[i][j] = __builtin_amdgcn_mfma_f32_16x16x32_bf16(ah[i], bh[j], acc[i][j], 0,0,0);
                    acc[i][j] = __builtin_amdgcn_mfma_f32_16x16x32_bf16(ah[i], bl[j], acc[i][j], 0,0,0);
                    acc[i][j] = __builtin_amdgcn_mfma_f32_16x16x32_bf16(al[i], bh[j], acc[i][j], 0,0,0);
                }
        }
    }
    #pragma unroll
    for (int i = 0; i < 4; i++)
      #pragma unroll
      for (int j = 0; j < 4; j++)
        #pragma unroll
        for (int r = 0; r < 4; r++) {
            int m = m0 + i*16 + fq*4 + r;
            int n = n0 + j*16 + fr;
            out[(size_t)m*NH + n] = tanhf(acc[i][j][r]);
        }
}

// ---------------- workspace layout (bytes) ----------------
// XW fp32 (B,T,4H)        @ 0            33,554,432  [dead after recurrence]
//   scores fp32 (B,T,S)   @ 0             8,388,608
//   attn_hi bf16 (B,T,S)  @ 8,388,608     4,194,304
//   attn_lo bf16 (B,T,S)  @ 12,582,912    4,194,304
// Hf fp32 (B,T,H)         @ 33,554,432    8,388,608
// Wc fp32 (B,T,H)         @ 41,943,040    8,388,608
// Wih_hi / Wih_lo         @ 50,331,648 / 52,428,800   (2MB each)
// Whh_hi / Whh_lo         @ 54,525,952 / 56,623,104   (2MB each)
// Wout_hi / Wout_lo       @ 58,720,256 / 59,768,832   (1MB each)
// ctxT bf16 (B,H,S)       @ 60,817,408   33,554,432
// c_st fp32 (B,H)         @ 94,371,840      131,072
// total                                  94,502,912

extern "C" void kernel_launch(void* const* d_in, const int* in_sizes, int n_in,
                              void* d_out, int out_size, void* d_ws, size_t ws_size,
                              hipStream_t stream) {
    const float* input = (const float*)d_in[0];
    const float* h0    = (const float*)d_in[1];
    const float* c0    = (const float*)d_in[2];
    const float* ctx   = (const float*)d_in[3];
    const float* W_ih  = (const float*)d_in[4];
    const float* b_ih  = (const float*)d_in[5];
    const float* W_hh  = (const float*)d_in[6];
    const float* b_hh  = (const float*)d_in[7];
    const float* W_out = (const float*)d_in[8];
    float* out = (float*)d_out;

    if (ws_size < 94502912u) return;  // fail loudly (d_out stays poisoned)

    char* ws = (char*)d_ws;
    float*          XW     = (float*)(ws + 0);
    float*          scores = (float*)(ws + 0);
    __hip_bfloat16* attn_h = (__hip_bfloat16*)(ws + 8388608);
    __hip_bfloat16* attn_l = (__hip_bfloat16*)(ws + 12582912);
    float*          Hf     = (float*)(ws + 33554432);
    float*          Wc     = (float*)(ws + 41943040);
    __hip_bfloat16* Wih_h  = (__hip_bfloat16*)(ws + 50331648);
    __hip_bfloat16* Wih_l  = (__hip_bfloat16*)(ws + 52428800);
    __hip_bfloat16* Whh_h  = (__hip_bfloat16*)(ws + 54525952);
    __hip_bfloat16* Whh_l  = (__hip_bfloat16*)(ws + 56623104);
    __hip_bfloat16* Wout_h = (__hip_bfloat16*)(ws + 58720256);
    __hip_bfloat16* Wout_l = (__hip_bfloat16*)(ws + 59768832);
    __hip_bfloat16* ctxT   = (__hip_bfloat16*)(ws + 60817408);
    float*          c_st   = (float*)(ws + 94371840);

    conv_split<<<2048, 256, 0, stream>>>(W_ih, Wih_h, Wih_l, G4*NI);
    conv_split<<<2048, 256, 0, stream>>>(W_hh, Whh_h, Whh_l, G4*NH);
    conv_split<<<1024, 256, 0, stream>>>(W_out, Wout_h, Wout_l, NH*H2);
    copy_f<<<128, 256, 0, stream>>>(c0, c_st, NB*NH);
    transpose_ctx<<<dim3(8,8,64), 256, 0, stream>>>(ctx, ctxT);
    gemm_xw<<<512, 256, 0, stream>>>(input, Wih_h, Wih_l, b_ih, b_hh, XW);

    float* hT = out + (size_t)BT*NH;
    float* cT = hT + NB*NH;
    for (int t = 0; t < NT_; t++) {
        const float* hprev = (t == 0) ? h0 : (Hf + (size_t)(t-1)*NH);
        int lda = (t == 0) ? NH : NT_*NH;
        lstm_step<<<16, 256, 0, stream>>>(hprev, lda, Whh_h, Whh_l, XW, c_st, Hf, hT, cT, t);
    }

    gemm_scores<<<128, 256, 0, stream>>>(Hf, ctx, scores);
    softmax_rows<<<1024, 256, 0, stream>>>(scores, attn_h, attn_l);
    gemm_wc<<<128, 256, 0, stream>>>(attn_h, attn_l, ctxT, Wc);
    gemm_out<<<128, 256, 0, stream>>>(Wc, Hf, Wout_h, Wout_l, out);
}

// Round 3
// 1314.058 us; speedup vs baseline: 1.5312x; 1.5312x over previous
//
#include <hip/hip_runtime.h>
#include <hip/hip_bf16.h>

// Problem constants
#define NB 64      // batch
#define NT_ 64     // time steps
#define NS 512     // source positions
#define NI 512     // input dim
#define NH 512     // hidden
#define G4 2048    // 4*H
#define H2 1024    // 2*H
#define BT (NB*NT_)
#define RBLK 64    // persistent-kernel blocks
#define CPB 8      // cells per block

typedef __attribute__((ext_vector_type(8))) short short8;   // 8 bf16 (4 VGPRs)
typedef __attribute__((ext_vector_type(4))) float f32x4;    // MFMA accumulator

__device__ __forceinline__ short f2bs(float f) {
    __hip_bfloat16 h = __float2bfloat16(f);
    return *reinterpret_cast<short*>(&h);
}
__device__ __forceinline__ float bs2f(short s) {
    unsigned int u = ((unsigned int)(unsigned short)s) << 16;
    union { unsigned int u; float f; } c; c.u = u; return c.f;
}
__device__ __forceinline__ short8 ld8b(const __hip_bfloat16* p) {
    return *reinterpret_cast<const short8*>(p);
}
// load 8 fp32, produce hi & lo bf16 fragments (x ~= hi + lo, rel err ~2^-16)
__device__ __forceinline__ void ld8f2(const float* p, short8& hi, short8& lo) {
    float4 a = *reinterpret_cast<const float4*>(p);
    float4 b = *reinterpret_cast<const float4*>(p + 4);
    float v[8] = {a.x,a.y,a.z,a.w,b.x,b.y,b.z,b.w};
    #pragma unroll
    for (int i = 0; i < 8; i++) {
        short h = f2bs(v[i]);
        hi[i] = h;
        lo[i] = f2bs(v[i] - bs2f(h));
    }
}
__device__ __forceinline__ float fsigm(float x){ return 1.f/(1.f + __expf(-x)); }
__device__ __forceinline__ float ftanh(float x){ float e = __expf(2.f*x); return 1.f - 2.f/(e + 1.f); }

// ---------------- conversions ----------------
__global__ __launch_bounds__(256) void conv_split(const float* __restrict__ s,
                                                  __hip_bfloat16* __restrict__ hi,
                                                  __hip_bfloat16* __restrict__ lo, int n) {
    for (int i = blockIdx.x*256 + threadIdx.x; i < n; i += gridDim.x*256) {
        float x = s[i];
        __hip_bfloat16 h = __float2bfloat16(x);
        hi[i] = h;
        lo[i] = __float2bfloat16(x - __bfloat162float(h));
    }
}

// h0 -> hs slot 0 (hi/lo), and zero the grid-barrier counter (deterministic per call)
__global__ __launch_bounds__(256) void hseq0_init(const float* __restrict__ h0,
                                                  __hip_bfloat16* __restrict__ hs_h,
                                                  __hip_bfloat16* __restrict__ hs_l,
                                                  unsigned* __restrict__ bar) {
    int i = blockIdx.x*256 + threadIdx.x;
    if (i == 0) bar[0] = 0u;
    if (i < NB*NH) {
        float x = h0[i];
        __hip_bfloat16 h = __float2bfloat16(x);
        hs_h[i] = h;
        hs_l[i] = __float2bfloat16(x - __bfloat162float(h));
    }
}

// ctxT[b][h][s] = bf16(ctx[s][b][h])  — for the wc GEMM (dot over s)
__global__ __launch_bounds__(256) void transpose_ctx(const float* __restrict__ ctx,
                                                     __hip_bfloat16* __restrict__ ctxT) {
    __shared__ float tile[64][65];
    int s0 = blockIdx.x*64, h0 = blockIdx.y*64, b = blockIdx.z;
    int tx = threadIdx.x & 63, ty = threadIdx.x >> 6;
    for (int i = 0; i < 16; i++) {
        int s = i*4 + ty;
        tile[s][tx] = ctx[(size_t)(s0+s)*NB*NH + (size_t)b*NH + h0 + tx];
    }
    __syncthreads();
    for (int i = 0; i < 16; i++) {
        int h = i*4 + ty;
        ctxT[(size_t)b*NH*NS + (size_t)(h0+h)*NS + s0 + tx] = __float2bfloat16(tile[tx][h]);
    }
}

// ---------------- XW = input @ W_ih^T + b_ih + b_hh  (M=4096,N=2048,K=512) ----------------
__global__ __launch_bounds__(256) void gemm_xw(const float* __restrict__ X,
                                               const __hip_bfloat16* __restrict__ Wh,
                                               const __hip_bfloat16* __restrict__ Wl,
                                               const float* __restrict__ b_ih,
                                               const float* __restrict__ b_hh,
                                               float* __restrict__ XW) {
    int wid = blockIdx.x*4 + (threadIdx.x>>6);
    int lane = threadIdx.x & 63;
    int m0 = (wid >> 5) * 64;
    int n0 = (wid & 31) * 64;
    int fr = lane & 15, fq = lane >> 4;
    f32x4 acc[4][4] = {};
    for (int kk = 0; kk < NI; kk += 32) {
        short8 ah[4], al[4], bh[4], bl[4];
        #pragma unroll
        for (int i = 0; i < 4; i++) ld8f2(X + (size_t)(m0+i*16+fr)*NI + kk + fq*8, ah[i], al[i]);
        #pragma unroll
        for (int j = 0; j < 4; j++) {
            bh[j] = ld8b(Wh + (size_t)(n0+j*16+fr)*NI + kk + fq*8);
            bl[j] = ld8b(Wl + (size_t)(n0+j*16+fr)*NI + kk + fq*8);
        }
        #pragma unroll
        for (int i = 0; i < 4; i++)
            #pragma unroll
            for (int j = 0; j < 4; j++) {
                acc[i][j] = __builtin_amdgcn_mfma_f32_16x16x32_bf16(ah[i], bh[j], acc[i][j], 0,0,0);
                acc[i][j] = __builtin_amdgcn_mfma_f32_16x16x32_bf16(ah[i], bl[j], acc[i][j], 0,0,0);
                acc[i][j] = __builtin_amdgcn_mfma_f32_16x16x32_bf16(al[i], bh[j], acc[i][j], 0,0,0);
            }
    }
    #pragma unroll
    for (int i = 0; i < 4; i++)
      #pragma unroll
      for (int j = 0; j < 4; j++)
        #pragma unroll
        for (int r = 0; r < 4; r++) {
            int m = m0 + i*16 + fq*4 + r;
            int n = n0 + j*16 + fr;
            XW[(size_t)m*G4 + n] = acc[i][j][r] + b_ih[n] + b_hh[n];
        }
}

// ---------------- persistent LSTM recurrence: all 64 steps in one kernel ----------------
// 64 blocks x 256 threads. Block bi owns cells [bi*8, bi*8+8) -> 32 gate columns.
// Whh slice (hi+lo) staged in LDS once (XOR-swizzled). c-state in registers.
// Per step: split-GEMM (2 M-halves x 2 K-halves over 4 waves) -> gates in LDS ->
// cell elementwise -> write h (bf16 hi/lo time-series + fp32 Hf) -> grid barrier.
__global__ __launch_bounds__(256) void lstm_persist(
    const float* __restrict__ c0,
    const __hip_bfloat16* __restrict__ Whh_h,
    const __hip_bfloat16* __restrict__ Whh_l,
    const float* __restrict__ XW,
    __hip_bfloat16* __restrict__ hs_h,   // (65,B,H) bf16 time-series
    __hip_bfloat16* __restrict__ hs_l,
    float* __restrict__ Hf,              // (B,T,H) fp32
    float* __restrict__ hT, float* __restrict__ cT,
    unsigned* __restrict__ bar)
{
    __shared__ __hip_bfloat16 Wh[32*512];   // 32KB, swizzled
    __shared__ __hip_bfloat16 Wl[32*512];   // 32KB
    __shared__ float gl[64][34];            // gates staging, padded
    int tid = threadIdx.x, bi = blockIdx.x;
    int lane = tid & 63, w = tid >> 6;
    int fr = lane & 15, fq = lane >> 4;

    // --- stage Whh slice into LDS (rows jl: gate g=jl>>3, cell bi*8+(jl&7)) ---
    {
        int jl = tid >> 3, ck8 = tid & 7;
        int grow = (jl >> 3) * NH + bi * CPB + (jl & 7);
        const short8* srcH = (const short8*)(Whh_h + (size_t)grow * NH);
        const short8* srcL = (const short8*)(Whh_l + (size_t)grow * NH);
        #pragma unroll
        for (int cc = 0; cc < 8; cc++) {
            int ck = ck8 * 8 + cc;                       // 16B chunk 0..63
            int sw = (ck * 16) ^ ((jl & 7) << 4);
            *(short8*)((char*)Wh + jl * 1024 + sw) = srcH[ck];
            *(short8*)((char*)Wl + jl * 1024 + sw) = srcL[ck];
        }
    }
    // --- c-state in registers: thread -> (batch eb, cells ec0..ec0+1) ---
    int eb  = tid >> 2;
    int ec0 = (tid & 3) * 2;
    float creg[2];
    creg[0] = c0[eb * NH + bi*CPB + ec0];
    creg[1] = c0[eb * NH + bi*CPB + ec0 + 1];
    __syncthreads();

    int m0 = (w & 1) * 32;      // M-half (batch rows)
    int kh = w >> 1;            // K-half
    int kbase = kh * 256;

    for (int t = 0; t < NT_; t++) {
        const __hip_bfloat16* Ah = hs_h + (size_t)t * NB * NH;
        const __hip_bfloat16* Al = hs_l + (size_t)t * NB * NH;

        // prefetch XW for this step (kh==0 waves add it)
        float xwv[2][2][4];
        if (kh == 0) {
            #pragma unroll
            for (int i = 0; i < 2; i++)
              #pragma unroll
              for (int j = 0; j < 2; j++)
                #pragma unroll
                for (int r = 0; r < 4; r++) {
                    int b  = m0 + i*16 + fq*4 + r;
                    int jl = j*16 + fr;
                    xwv[i][j][r] = XW[((size_t)b*NT_ + t)*G4 + (jl>>3)*NH + bi*CPB + (jl&7)];
                }
        }

        f32x4 acc[2][2] = {};
        #pragma unroll
        for (int kk = 0; kk < 256; kk += 32) {
            short8 a_h[2], a_l[2], b_h[2], b_l[2];
            #pragma unroll
            for (int i = 0; i < 2; i++) {
                size_t off = (size_t)(m0 + i*16 + fr) * NH + kbase + kk + fq*8;
                a_h[i] = ld8b(Ah + off);
                a_l[i] = ld8b(Al + off);
            }
            #pragma unroll
            for (int j = 0; j < 2; j++) {
                int jl = j*16 + fr;
                int byt = jl*1024 + ((((kbase + kk + fq*8)*2)) ^ ((jl & 7) << 4));
                b_h[j] = *(const short8*)((const char*)Wh + byt);
                b_l[j] = *(const short8*)((const char*)Wl + byt);
            }
            #pragma unroll
            for (int i = 0; i < 2; i++)
                #pragma unroll
                for (int j = 0; j < 2; j++) {
                    acc[i][j] = __builtin_amdgcn_mfma_f32_16x16x32_bf16(a_h[i], b_h[j], acc[i][j], 0,0,0);
                    acc[i][j] = __builtin_amdgcn_mfma_f32_16x16x32_bf16(a_h[i], b_l[j], acc[i][j], 0,0,0);
                    acc[i][j] = __builtin_amdgcn_mfma_f32_16x16x32_bf16(a_l[i], b_h[j], acc[i][j], 0,0,0);
                }
        }

        if (kh == 0) {
            #pragma unroll
            for (int i = 0; i < 2; i++)
              #pragma unroll
              for (int j = 0; j < 2; j++)
                #pragma unroll
                for (int r = 0; r < 4; r++)
                    gl[m0 + i*16 + fq*4 + r][j*16 + fr] = acc[i][j][r] + xwv[i][j][r];
        }
        __syncthreads();
        if (kh == 1) {
            #pragma unroll
            for (int i = 0; i < 2; i++)
              #pragma unroll
              for (int j = 0; j < 2; j++)
                #pragma unroll
                for (int r = 0; r < 4; r++)
                    gl[m0 + i*16 + fq*4 + r][j*16 + fr] += acc[i][j][r];
        }
        __syncthreads();

        // --- cell elementwise (2 cells/thread), write h ---
        {
            float hv[2];
            #pragma unroll
            for (int u = 0; u < 2; u++) {
                int cl = ec0 + u;
                float gi = gl[eb][cl];
                float gf = gl[eb][8  + cl];
                float gg = gl[eb][16 + cl];
                float go = gl[eb][24 + cl];
                float ct = fsigm(gf)*creg[u] + fsigm(gi)*ftanh(gg);
                hv[u] = fsigm(go)*ftanh(ct);
                creg[u] = ct;
            }
            int hcol = bi*CPB + ec0;
            size_t hoff = (size_t)(t+1)*NB*NH + (size_t)eb*NH + hcol;
            #pragma unroll
            for (int u = 0; u < 2; u++) {
                __hip_bfloat16 hb = __float2bfloat16(hv[u]);
                hs_h[hoff + u] = hb;
                hs_l[hoff + u] = __float2bfloat16(hv[u] - __bfloat162float(hb));
            }
            *(float2*)&Hf[((size_t)eb*NT_ + t)*NH + hcol] = make_float2(hv[0], hv[1]);
            if (t == NT_-1) {
                *(float2*)&hT[(size_t)eb*NH + hcol] = make_float2(hv[0], hv[1]);
                *(float2*)&cT[(size_t)eb*NH + hcol] = make_float2(creg[0], creg[1]);
            }
        }

        // --- grid barrier (agent scope) ---
        __threadfence();
        __syncthreads();
        if (tid == 0) {
            unsigned target = (unsigned)(RBLK * (t+1));
            __hip_atomic_fetch_add(&bar[0], 1u, __ATOMIC_ACQ_REL, __HIP_MEMORY_SCOPE_AGENT);
            int guard = 0;
            while (__hip_atomic_load(&bar[0], __ATOMIC_ACQUIRE, __HIP_MEMORY_SCOPE_AGENT) < target) {
                __builtin_amdgcn_s_sleep(4);
                if (++guard > (1<<22)) break;   // safety: fail loud (bad output) rather than hang
            }
        }
        __syncthreads();
        __threadfence();
    }
}

// ---------------- scores[b,t,s] = Hf[b,t,:] . ctx[s,b,:]  (per-b M=64,N=512,K=512) ----------------
__global__ __launch_bounds__(256) void gemm_scores(const float* __restrict__ Hf,
                                                   const float* __restrict__ ctx,
                                                   float* __restrict__ scores) {
    int wid = blockIdx.x*4 + (threadIdx.x>>6);
    int lane = threadIdx.x & 63;
    int b  = wid >> 3;
    int n0 = (wid & 7) * 64;
    int fr = lane & 15, fq = lane >> 4;
    const float* Ab = Hf + (size_t)b*NT_*NH;
    const float* Bb = ctx + (size_t)b*NH;
    f32x4 acc[4][4] = {};
    for (int kk = 0; kk < NH; kk += 32) {
        short8 ah[4], al[4], bh[4], bl[4];
        #pragma unroll
        for (int i = 0; i < 4; i++) ld8f2(Ab + (size_t)(i*16+fr)*NH + kk + fq*8, ah[i], al[i]);
        #pragma unroll
        for (int j = 0; j < 4; j++) ld8f2(Bb + (size_t)(n0+j*16+fr)*NB*NH + kk + fq*8, bh[j], bl[j]);
        #pragma unroll
        for (int i = 0; i < 4; i++)
            #pragma unroll
            for (int j = 0; j < 4; j++) {
                acc[i][j] = __builtin_amdgcn_mfma_f32_16x16x32_bf16(ah[i], bh[j], acc[i][j], 0,0,0);
                acc[i][j] = __builtin_amdgcn_mfma_f32_16x16x32_bf16(ah[i], bl[j], acc[i][j], 0,0,0);
                acc[i][j] = __builtin_amdgcn_mfma_f32_16x16x32_bf16(al[i], bh[j], acc[i][j], 0,0,0);
            }
    }
    #pragma unroll
    for (int i = 0; i < 4; i++)
      #pragma unroll
      for (int j = 0; j < 4; j++)
        #pragma unroll
        for (int r = 0; r < 4; r++) {
            int t = i*16 + fq*4 + r;
            int s = n0 + j*16 + fr;
            scores[((size_t)b*NT_ + t)*NS + s] = acc[i][j][r];
        }
}

// ---------------- row softmax over S, output attn hi/lo bf16 ----------------
__global__ __launch_bounds__(256) void softmax_rows(const float* __restrict__ scores,
                                                    __hip_bfloat16* __restrict__ ah,
                                                    __hip_bfloat16* __restrict__ al) {
    int row = blockIdx.x*4 + (threadIdx.x>>6);
    int lane = threadIdx.x & 63;
    const float* r = scores + (size_t)row*NS;
    float v[8], mx = -1e30f;
    #pragma unroll
    for (int i = 0; i < 8; i++) { v[i] = r[lane + i*64]; mx = fmaxf(mx, v[i]); }
    #pragma unroll
    for (int off = 32; off; off >>= 1) mx = fmaxf(mx, __shfl_xor(mx, off));
    float sum = 0.f;
    #pragma unroll
    for (int i = 0; i < 8; i++) { v[i] = __expf(v[i]-mx); sum += v[i]; }
    #pragma unroll
    for (int off = 32; off; off >>= 1) sum += __shfl_xor(sum, off);
    float inv = 1.f/sum;
    #pragma unroll
    for (int i = 0; i < 8; i++) {
        float a = v[i]*inv;
        __hip_bfloat16 h = __float2bfloat16(a);
        ah[(size_t)row*NS + lane + i*64] = h;
        al[(size_t)row*NS + lane + i*64] = __float2bfloat16(a - __bfloat162float(h));
    }
}

// ---------------- Wc[b,t,h] = sum_s attn[b,t,s]*ctxT[b,h,s]  (fp32 out) ----------------
__global__ __launch_bounds__(256) void gemm_wc(const __hip_bfloat16* __restrict__ Ah,
                                               const __hip_bfloat16* __restrict__ Al,
                                               const __hip_bfloat16* __restrict__ ctxT,
                                               float* __restrict__ Wc) {
    int wid = blockIdx.x*4 + (threadIdx.x>>6);
    int lane = threadIdx.x & 63;
    int b  = wid >> 3;
    int n0 = (wid & 7) * 64;
    int fr = lane & 15, fq = lane >> 4;
    const __hip_bfloat16* Abh = Ah + (size_t)b*NT_*NS;
    const __hip_bfloat16* Abl = Al + (size_t)b*NT_*NS;
    const __hip_bfloat16* Bb  = ctxT + (size_t)b*NH*NS;
    f32x4 acc[4][4] = {};
    for (int kk = 0; kk < NS; kk += 32) {
        short8 ah[4], al[4], bb[4];
        #pragma unroll
        for (int i = 0; i < 4; i++) {
            ah[i] = ld8b(Abh + (size_t)(i*16+fr)*NS + kk + fq*8);
            al[i] = ld8b(Abl + (size_t)(i*16+fr)*NS + kk + fq*8);
        }
        #pragma unroll
        for (int j = 0; j < 4; j++) bb[j] = ld8b(Bb + (size_t)(n0+j*16+fr)*NS + kk + fq*8);
        #pragma unroll
        for (int i = 0; i < 4; i++)
            #pragma unroll
            for (int j = 0; j < 4; j++) {
                acc[i][j] = __builtin_amdgcn_mfma_f32_16x16x32_bf16(ah[i], bb[j], acc[i][j], 0,0,0);
                acc[i][j] = __builtin_amdgcn_mfma_f32_16x16x32_bf16(al[i], bb[j], acc[i][j], 0,0,0);
            }
    }
    #pragma unroll
    for (int i = 0; i < 4; i++)
      #pragma unroll
      for (int j = 0; j < 4; j++)
        #pragma unroll
        for (int r = 0; r < 4; r++) {
            int t = i*16 + fq*4 + r;
            int h = n0 + j*16 + fr;
            Wc[((size_t)b*NT_ + t)*NH + h] = acc[i][j][r];
        }
}

// ---------------- out = tanh([Wc|Hf] @ W_out^T)  (M=4096,N=512,K=1024) ----------------
__global__ __launch_bounds__(256) void gemm_out(const float* __restrict__ Wc,
                                                const float* __restrict__ Hf,
                                                const __hip_bfloat16* __restrict__ Wh,
                                                const __hip_bfloat16* __restrict__ Wl,
                                                float* __restrict__ out) {
    int wid = blockIdx.x*4 + (threadIdx.x>>6);
    int lane = threadIdx.x & 63;
    int m0 = (wid >> 3) * 64;
    int n0 = (wid & 7) * 64;
    int fr = lane & 15, fq = lane >> 4;
    f32x4 acc[4][4] = {};
    #pragma unroll 1
    for (int half = 0; half < 2; half++) {
        const float* Am = half ? Hf : Wc;
        int koff = half ? NH : 0;
        for (int kk = 0; kk < NH; kk += 32) {
            short8 ah[4], al[4], bh[4], bl[4];
            #pragma unroll
            for (int i = 0; i < 4; i++) ld8f2(Am + (size_t)(m0+i*16+fr)*NH + kk + fq*8, ah[i], al[i]);
            #pragma unroll
            for (int j = 0; j < 4; j++) {
                bh[j] = ld8b(Wh + (size_t)(n0+j*16+fr)*H2 + koff + kk + fq*8);
                bl[j] = ld8b(Wl + (size_t)(n0+j*16+fr)*H2 + koff + kk + fq*8);
            }
            #pragma unroll
            for (int i = 0; i < 4; i++)
                #pragma unroll
                for (int j = 0; j < 4; j++) {
                    acc[i][j] = __builtin_amdgcn_mfma_f32_16x16x32_bf16(ah[i], bh[j], acc[i][j], 0,0,0);
                    acc[i][j] = __builtin_amdgcn_mfma_f32_16x16x32_bf16(ah[i], bl[j], acc[i][j], 0,0,0);
                    acc[i][j] = __builtin_amdgcn_mfma_f32_16x16x32_bf16(al[i], bh[j], acc[i][j], 0,0,0);
                }
        }
    }
    #pragma unroll
    for (int i = 0; i < 4; i++)
      #pragma unroll
      for (int j = 0; j < 4; j++)
        #pragma unroll
        for (int r = 0; r < 4; r++) {
            int m = m0 + i*16 + fq*4 + r;
            int n = n0 + j*16 + fr;
            out[(size_t)m*NH + n] = ftanh(acc[i][j][r]);
        }
}

// ---------------- workspace layout (bytes), total 94,371,840 (proven available) ----------------
// XW fp32 (B,T,4H)        @ 0            33,554,432  [live: gemm_xw -> recurrence]
//   scores fp32 (B,T,S)   @ 0             8,388,608  [post-recurrence overlay]
//   attn_hi bf16 (B,T,S)  @ 8,388,608     4,194,304
//   attn_lo bf16 (B,T,S)  @ 12,582,912    4,194,304
// Hf fp32 (B,T,H)         @ 33,554,432    8,388,608
// Wc fp32 (B,T,H)         @ 41,943,040    8,388,608
// Wih_hi / Wih_lo         @ 50,331,648 / 52,428,800
// Whh_hi / Whh_lo         @ 54,525,952 / 56,623,104
// Wout_hi / Wout_lo       @ 58,720,256 / 59,768,832
// ctxT bf16 (B,H,S)       @ 60,817,408   33,554,432  [written AFTER recurrence]
//   hs_h bf16 (65,B,H)    @ 60,817,408    4,259,840  [recurrence-only overlay]
//   hs_l bf16 (65,B,H)    @ 65,077,248    4,259,840
//   barrier u32           @ 69,337,088            4

extern "C" void kernel_launch(void* const* d_in, const int* in_sizes, int n_in,
                              void* d_out, int out_size, void* d_ws, size_t ws_size,
                              hipStream_t stream) {
    const float* input = (const float*)d_in[0];
    const float* h0    = (const float*)d_in[1];
    const float* c0    = (const float*)d_in[2];
    const float* ctx   = (const float*)d_in[3];
    const float* W_ih  = (const float*)d_in[4];
    const float* b_ih  = (const float*)d_in[5];
    const float* W_hh  = (const float*)d_in[6];
    const float* b_hh  = (const float*)d_in[7];
    const float* W_out = (const float*)d_in[8];
    float* out = (float*)d_out;

    if (ws_size < 94371840u) return;  // fail loudly (d_out stays poisoned)

    char* ws = (char*)d_ws;
    float*          XW     = (float*)(ws + 0);
    float*          scores = (float*)(ws + 0);
    __hip_bfloat16* attn_h = (__hip_bfloat16*)(ws + 8388608);
    __hip_bfloat16* attn_l = (__hip_bfloat16*)(ws + 12582912);
    float*          Hf     = (float*)(ws + 33554432);
    float*          Wc     = (float*)(ws + 41943040);
    __hip_bfloat16* Wih_h  = (__hip_bfloat16*)(ws + 50331648);
    __hip_bfloat16* Wih_l  = (__hip_bfloat16*)(ws + 52428800);
    __hip_bfloat16* Whh_h  = (__hip_bfloat16*)(ws + 54525952);
    __hip_bfloat16* Whh_l  = (__hip_bfloat16*)(ws + 56623104);
    __hip_bfloat16* Wout_h = (__hip_bfloat16*)(ws + 58720256);
    __hip_bfloat16* Wout_l = (__hip_bfloat16*)(ws + 59768832);
    __hip_bfloat16* ctxT   = (__hip_bfloat16*)(ws + 60817408);
    __hip_bfloat16* hs_h   = (__hip_bfloat16*)(ws + 60817408);
    __hip_bfloat16* hs_l   = (__hip_bfloat16*)(ws + 65077248);
    unsigned*       bar    = (unsigned*)(ws + 69337088);

    conv_split<<<2048, 256, 0, stream>>>(W_ih, Wih_h, Wih_l, G4*NI);
    conv_split<<<2048, 256, 0, stream>>>(W_hh, Whh_h, Whh_l, G4*NH);
    conv_split<<<1024, 256, 0, stream>>>(W_out, Wout_h, Wout_l, NH*H2);
    hseq0_init<<<128, 256, 0, stream>>>(h0, hs_h, hs_l, bar);
    gemm_xw<<<512, 256, 0, stream>>>(input, Wih_h, Wih_l, b_ih, b_hh, XW);

    float* hT = out + (size_t)BT*NH;
    float* cT = hT + NB*NH;
    lstm_persist<<<RBLK, 256, 0, stream>>>(c0, Whh_h, Whh_l, XW, hs_h, hs_l, Hf, hT, cT, bar);

    transpose_ctx<<<dim3(8,8,64), 256, 0, stream>>>(ctx, ctxT);
    gemm_scores<<<128, 256, 0, stream>>>(Hf, ctx, scores);
    softmax_rows<<<1024, 256, 0, stream>>>(scores, attn_h, attn_l);
    gemm_wc<<<128, 256, 0, stream>>>(attn_h, attn_l, ctxT, Wc);
    gemm_out<<<128, 256, 0, stream>>>(Wc, Hf, Wout_h, Wout_l, out);
}

// Round 4
// 704.666 us; speedup vs baseline: 2.8554x; 1.8648x over previous
//
#include <hip/hip_runtime.h>
#include <hip/hip_bf16.h>

// Problem constants
#define NB 64      // batch
#define NT_ 64     // time steps
#define NS 512     // source positions
#define NI 512     // input dim
#define NH 512     // hidden
#define G4 2048    // 4*H
#define H2 1024    // 2*H
#define BT (NB*NT_)
#define RBLK 64    // persistent-kernel blocks
#define CPB 8      // cells per block

typedef __attribute__((ext_vector_type(8))) short short8;   // 8 bf16 (4 VGPRs)
typedef __attribute__((ext_vector_type(4))) float f32x4;    // MFMA accumulator

__device__ __forceinline__ short f2bs(float f) {
    __hip_bfloat16 h = __float2bfloat16(f);
    return *reinterpret_cast<short*>(&h);
}
__device__ __forceinline__ float bs2f(short s) {
    unsigned int u = ((unsigned int)(unsigned short)s) << 16;
    union { unsigned int u; float f; } c; c.u = u; return c.f;
}
__device__ __forceinline__ short8 ld8b(const __hip_bfloat16* p) {
    return *reinterpret_cast<const short8*>(p);
}
// load 8 fp32, produce hi & lo bf16 fragments (x ~= hi + lo, rel err ~2^-16)
__device__ __forceinline__ void ld8f2(const float* p, short8& hi, short8& lo) {
    float4 a = *reinterpret_cast<const float4*>(p);
    float4 b = *reinterpret_cast<const float4*>(p + 4);
    float v[8] = {a.x,a.y,a.z,a.w,b.x,b.y,b.z,b.w};
    #pragma unroll
    for (int i = 0; i < 8; i++) {
        short h = f2bs(v[i]);
        hi[i] = h;
        lo[i] = f2bs(v[i] - bs2f(h));
    }
}
__device__ __forceinline__ float fsigm(float x){ return 1.f/(1.f + __expf(-x)); }
__device__ __forceinline__ float ftanh(float x){ float e = __expf(2.f*x); return 1.f - 2.f/(e + 1.f); }

// ---------------- conversions ----------------
__global__ __launch_bounds__(256) void conv_split(const float* __restrict__ s,
                                                  __hip_bfloat16* __restrict__ hi,
                                                  __hip_bfloat16* __restrict__ lo, int n) {
    for (int i = blockIdx.x*256 + threadIdx.x; i < n; i += gridDim.x*256) {
        float x = s[i];
        __hip_bfloat16 h = __float2bfloat16(x);
        hi[i] = h;
        lo[i] = __float2bfloat16(x - __bfloat162float(h));
    }
}

// h0 -> hs slot 0 (hi/lo), and zero the grid-barrier counter (deterministic per call)
__global__ __launch_bounds__(256) void hseq0_init(const float* __restrict__ h0,
                                                  __hip_bfloat16* __restrict__ hs_h,
                                                  __hip_bfloat16* __restrict__ hs_l,
                                                  unsigned* __restrict__ bar) {
    int i = blockIdx.x*256 + threadIdx.x;
    if (i == 0) bar[0] = 0u;
    if (i < NB*NH) {
        float x = h0[i];
        __hip_bfloat16 h = __float2bfloat16(x);
        hs_h[i] = h;
        hs_l[i] = __float2bfloat16(x - __bfloat162float(h));
    }
}

// ctxT[b][h][s] = bf16(ctx[s][b][h])  — for the wc GEMM (dot over s)
__global__ __launch_bounds__(256) void transpose_ctx(const float* __restrict__ ctx,
                                                     __hip_bfloat16* __restrict__ ctxT) {
    __shared__ float tile[64][65];
    int s0 = blockIdx.x*64, h0 = blockIdx.y*64, b = blockIdx.z;
    int tx = threadIdx.x & 63, ty = threadIdx.x >> 6;
    for (int i = 0; i < 16; i++) {
        int s = i*4 + ty;
        tile[s][tx] = ctx[(size_t)(s0+s)*NB*NH + (size_t)b*NH + h0 + tx];
    }
    __syncthreads();
    for (int i = 0; i < 16; i++) {
        int h = i*4 + ty;
        ctxT[(size_t)b*NH*NS + (size_t)(h0+h)*NS + s0 + tx] = __float2bfloat16(tile[tx][h]);
    }
}

// ---------------- XW = input @ W_ih^T + b_ih + b_hh  (M=4096,N=2048,K=512) ----------------
__global__ __launch_bounds__(256) void gemm_xw(const float* __restrict__ X,
                                               const __hip_bfloat16* __restrict__ Wh,
                                               const __hip_bfloat16* __restrict__ Wl,
                                               const float* __restrict__ b_ih,
                                               const float* __restrict__ b_hh,
                                               float* __restrict__ XW) {
    int wid = blockIdx.x*4 + (threadIdx.x>>6);
    int lane = threadIdx.x & 63;
    int m0 = (wid >> 5) * 64;
    int n0 = (wid & 31) * 64;
    int fr = lane & 15, fq = lane >> 4;
    f32x4 acc[4][4] = {};
    for (int kk = 0; kk < NI; kk += 32) {
        short8 ah[4], al[4], bh[4], bl[4];
        #pragma unroll
        for (int i = 0; i < 4; i++) ld8f2(X + (size_t)(m0+i*16+fr)*NI + kk + fq*8, ah[i], al[i]);
        #pragma unroll
        for (int j = 0; j < 4; j++) {
            bh[j] = ld8b(Wh + (size_t)(n0+j*16+fr)*NI + kk + fq*8);
            bl[j] = ld8b(Wl + (size_t)(n0+j*16+fr)*NI + kk + fq*8);
        }
        #pragma unroll
        for (int i = 0; i < 4; i++)
            #pragma unroll
            for (int j = 0; j < 4; j++) {
                acc[i][j] = __builtin_amdgcn_mfma_f32_16x16x32_bf16(ah[i], bh[j], acc[i][j], 0,0,0);
                acc[i][j] = __builtin_amdgcn_mfma_f32_16x16x32_bf16(ah[i], bl[j], acc[i][j], 0,0,0);
                acc[i][j] = __builtin_amdgcn_mfma_f32_16x16x32_bf16(al[i], bh[j], acc[i][j], 0,0,0);
            }
    }
    #pragma unroll
    for (int i = 0; i < 4; i++)
      #pragma unroll
      for (int j = 0; j < 4; j++)
        #pragma unroll
        for (int r = 0; r < 4; r++) {
            int m = m0 + i*16 + fq*4 + r;
            int n = n0 + j*16 + fr;
            XW[(size_t)m*G4 + n] = acc[i][j][r] + b_ih[n] + b_hh[n];
        }
}

// ---------------- persistent LSTM recurrence: all 64 steps in one kernel ----------------
// 64 blocks x 256 threads. Block bi owns cells [bi*8, bi*8+8) -> 32 gate columns.
// Whh slice (hi+lo) staged in LDS once (XOR-swizzled). c-state in registers.
// Cross-XCD h exchange WITHOUT cache fences:
//   - h stores are device-scope relaxed atomic u32 (write-through to the coherence
//     point / L3; XCD L2s are not flushed)
//   - h loads are plain: hs is a time-series, so slot t+1 lines are never in a
//     reader's L2 before their write (dispatch-start invalidate handles replays)
//   - barrier counter uses RELAXED device-scope atomics only (an ACQUIRE polling
//     load would emit an L2 invalidate per poll)
//   - ordering: __syncthreads drains each wave's vmem (compiler-emitted
//     s_waitcnt vmcnt(0) before s_barrier) before block 'arrives'
__global__ __launch_bounds__(256, 1) void lstm_persist(
    const float* __restrict__ c0,
    const __hip_bfloat16* __restrict__ Whh_h,
    const __hip_bfloat16* __restrict__ Whh_l,
    const float* __restrict__ XW,
    __hip_bfloat16* __restrict__ hs_h,   // (65,B,H) bf16 time-series
    __hip_bfloat16* __restrict__ hs_l,
    float* __restrict__ Hf,              // (B,T,H) fp32
    float* __restrict__ hT, float* __restrict__ cT,
    unsigned* __restrict__ bar)
{
    __shared__ __hip_bfloat16 Wh[32*512];   // 32KB, swizzled
    __shared__ __hip_bfloat16 Wl[32*512];   // 32KB
    __shared__ float gl[64][34];            // gates staging, padded
    int tid = threadIdx.x, bi = blockIdx.x;
    int lane = tid & 63, w = tid >> 6;
    int fr = lane & 15, fq = lane >> 4;

    // --- stage Whh slice into LDS (rows jl: gate g=jl>>3, cell bi*8+(jl&7)) ---
    {
        int jl = tid >> 3, ck8 = tid & 7;
        int grow = (jl >> 3) * NH + bi * CPB + (jl & 7);
        const short8* srcH = (const short8*)(Whh_h + (size_t)grow * NH);
        const short8* srcL = (const short8*)(Whh_l + (size_t)grow * NH);
        #pragma unroll
        for (int cc = 0; cc < 8; cc++) {
            int ck = ck8 * 8 + cc;                       // 16B chunk 0..63
            int sw = (ck * 16) ^ ((jl & 7) << 4);
            *(short8*)((char*)Wh + jl * 1024 + sw) = srcH[ck];
            *(short8*)((char*)Wl + jl * 1024 + sw) = srcL[ck];
        }
    }
    // --- c-state in registers: thread -> (batch eb, cells ec0..ec0+1) ---
    int eb  = tid >> 2;
    int ec0 = (tid & 3) * 2;
    float creg[2];
    creg[0] = c0[eb * NH + bi*CPB + ec0];
    creg[1] = c0[eb * NH + bi*CPB + ec0 + 1];
    __syncthreads();

    int m0 = (w & 1) * 32;      // M-half (batch rows)
    int kh = w >> 1;            // K-half
    int kbase = kh * 256;

    for (int t = 0; t < NT_; t++) {
        const __hip_bfloat16* Ah = hs_h + (size_t)t * NB * NH;
        const __hip_bfloat16* Al = hs_l + (size_t)t * NB * NH;

        // XW gather for this step (kh==0 waves add it)
        float xwv[2][2][4];
        if (kh == 0) {
            #pragma unroll
            for (int i = 0; i < 2; i++)
              #pragma unroll
              for (int j = 0; j < 2; j++)
                #pragma unroll
                for (int r = 0; r < 4; r++) {
                    int b  = m0 + i*16 + fq*4 + r;
                    int jl = j*16 + fr;
                    xwv[i][j][r] = XW[((size_t)b*NT_ + t)*G4 + (jl>>3)*NH + bi*CPB + (jl&7)];
                }
        }

        f32x4 acc[2][2] = {};
        #pragma unroll
        for (int kk = 0; kk < 256; kk += 32) {
            short8 a_h[2], a_l[2], b_h[2], b_l[2];
            #pragma unroll
            for (int i = 0; i < 2; i++) {
                size_t off = (size_t)(m0 + i*16 + fr) * NH + kbase + kk + fq*8;
                a_h[i] = ld8b(Ah + off);
                a_l[i] = ld8b(Al + off);
            }
            #pragma unroll
            for (int j = 0; j < 2; j++) {
                int jl = j*16 + fr;
                int byt = jl*1024 + ((((kbase + kk + fq*8)*2)) ^ ((jl & 7) << 4));
                b_h[j] = *(const short8*)((const char*)Wh + byt);
                b_l[j] = *(const short8*)((const char*)Wl + byt);
            }
            #pragma unroll
            for (int i = 0; i < 2; i++)
                #pragma unroll
                for (int j = 0; j < 2; j++) {
                    acc[i][j] = __builtin_amdgcn_mfma_f32_16x16x32_bf16(a_h[i], b_h[j], acc[i][j], 0,0,0);
                    acc[i][j] = __builtin_amdgcn_mfma_f32_16x16x32_bf16(a_h[i], b_l[j], acc[i][j], 0,0,0);
                    acc[i][j] = __builtin_amdgcn_mfma_f32_16x16x32_bf16(a_l[i], b_h[j], acc[i][j], 0,0,0);
                }
        }

        if (kh == 0) {
            #pragma unroll
            for (int i = 0; i < 2; i++)
              #pragma unroll
              for (int j = 0; j < 2; j++)
                #pragma unroll
                for (int r = 0; r < 4; r++)
                    gl[m0 + i*16 + fq*4 + r][j*16 + fr] = acc[i][j][r] + xwv[i][j][r];
        }
        __syncthreads();
        if (kh == 1) {
            #pragma unroll
            for (int i = 0; i < 2; i++)
              #pragma unroll
              for (int j = 0; j < 2; j++)
                #pragma unroll
                for (int r = 0; r < 4; r++)
                    gl[m0 + i*16 + fq*4 + r][j*16 + fr] += acc[i][j][r];
        }
        __syncthreads();

        // --- cell elementwise (2 cells/thread), write h ---
        {
            float hv[2];
            #pragma unroll
            for (int u = 0; u < 2; u++) {
                int cl = ec0 + u;
                float gi = gl[eb][cl];
                float gf = gl[eb][8  + cl];
                float gg = gl[eb][16 + cl];
                float go = gl[eb][24 + cl];
                float ct = fsigm(gf)*creg[u] + fsigm(gi)*ftanh(gg);
                hv[u] = fsigm(go)*ftanh(ct);
                creg[u] = ct;
            }
            int hcol = bi*CPB + ec0;
            size_t hoff = (size_t)(t+1)*NB*NH + (size_t)eb*NH + hcol;
            // pack 2 cells into one u32; device-scope store -> write-through to L3
            unsigned short h0b = (unsigned short)f2bs(hv[0]);
            unsigned short h1b = (unsigned short)f2bs(hv[1]);
            unsigned ph = (unsigned)h0b | ((unsigned)h1b << 16);
            unsigned short l0b = (unsigned short)f2bs(hv[0] - bs2f((short)h0b));
            unsigned short l1b = (unsigned short)f2bs(hv[1] - bs2f((short)h1b));
            unsigned pl = (unsigned)l0b | ((unsigned)l1b << 16);
            __hip_atomic_store((unsigned*)&hs_h[hoff], ph, __ATOMIC_RELAXED, __HIP_MEMORY_SCOPE_AGENT);
            __hip_atomic_store((unsigned*)&hs_l[hoff], pl, __ATOMIC_RELAXED, __HIP_MEMORY_SCOPE_AGENT);
            *(float2*)&Hf[((size_t)eb*NT_ + t)*NH + hcol] = make_float2(hv[0], hv[1]);
            if (t == NT_-1) {
                *(float2*)&hT[(size_t)eb*NH + hcol] = make_float2(hv[0], hv[1]);
                *(float2*)&cT[(size_t)eb*NH + hcol] = make_float2(creg[0], creg[1]);
            }
        }

        // --- grid barrier: relaxed device-scope counter, no cache maintenance ---
        asm volatile("s_waitcnt vmcnt(0)" ::: "memory");   // belt-and-braces drain
        __syncthreads();                                   // all waves' stores drained
        if (tid == 0) {
            unsigned target = (unsigned)(RBLK * (t+1));
            __hip_atomic_fetch_add(&bar[0], 1u, __ATOMIC_RELAXED, __HIP_MEMORY_SCOPE_AGENT);
            int guard = 0;
            while (__hip_atomic_load(&bar[0], __ATOMIC_RELAXED, __HIP_MEMORY_SCOPE_AGENT) < target) {
                __builtin_amdgcn_s_sleep(2);
                if (++guard > (1<<24)) break;   // safety: fail loud rather than hang
            }
        }
        __syncthreads();
    }
}

// ---------------- scores[b,t,s] = Hf[b,t,:] . ctx[s,b,:]  (per-b M=64,N=512,K=512) ----------------
__global__ __launch_bounds__(256) void gemm_scores(const float* __restrict__ Hf,
                                                   const float* __restrict__ ctx,
                                                   float* __restrict__ scores) {
    int wid = blockIdx.x*4 + (threadIdx.x>>6);
    int lane = threadIdx.x & 63;
    int b  = wid >> 3;
    int n0 = (wid & 7) * 64;
    int fr = lane & 15, fq = lane >> 4;
    const float* Ab = Hf + (size_t)b*NT_*NH;
    const float* Bb = ctx + (size_t)b*NH;
    f32x4 acc[4][4] = {};
    for (int kk = 0; kk < NH; kk += 32) {
        short8 ah[4], al[4], bh[4], bl[4];
        #pragma unroll
        for (int i = 0; i < 4; i++) ld8f2(Ab + (size_t)(i*16+fr)*NH + kk + fq*8, ah[i], al[i]);
        #pragma unroll
        for (int j = 0; j < 4; j++) ld8f2(Bb + (size_t)(n0+j*16+fr)*NB*NH + kk + fq*8, bh[j], bl[j]);
        #pragma unroll
        for (int i = 0; i < 4; i++)
            #pragma unroll
            for (int j = 0; j < 4; j++) {
                acc[i][j] = __builtin_amdgcn_mfma_f32_16x16x32_bf16(ah[i], bh[j], acc[i][j], 0,0,0);
                acc[i][j] = __builtin_amdgcn_mfma_f32_16x16x32_bf16(ah[i], bl[j], acc[i][j], 0,0,0);
                acc[i][j] = __builtin_amdgcn_mfma_f32_16x16x32_bf16(al[i], bh[j], acc[i][j], 0,0,0);
            }
    }
    #pragma unroll
    for (int i = 0; i < 4; i++)
      #pragma unroll
      for (int j = 0; j < 4; j++)
        #pragma unroll
        for (int r = 0; r < 4; r++) {
            int t = i*16 + fq*4 + r;
            int s = n0 + j*16 + fr;
            scores[((size_t)b*NT_ + t)*NS + s] = acc[i][j][r];
        }
}

// ---------------- row softmax over S, output attn hi/lo bf16 ----------------
__global__ __launch_bounds__(256) void softmax_rows(const float* __restrict__ scores,
                                                    __hip_bfloat16* __restrict__ ah,
                                                    __hip_bfloat16* __restrict__ al) {
    int row = blockIdx.x*4 + (threadIdx.x>>6);
    int lane = threadIdx.x & 63;
    const float* r = scores + (size_t)row*NS;
    float v[8], mx = -1e30f;
    #pragma unroll
    for (int i = 0; i < 8; i++) { v[i] = r[lane + i*64]; mx = fmaxf(mx, v[i]); }
    #pragma unroll
    for (int off = 32; off; off >>= 1) mx = fmaxf(mx, __shfl_xor(mx, off));
    float sum = 0.f;
    #pragma unroll
    for (int i = 0; i < 8; i++) { v[i] = __expf(v[i]-mx); sum += v[i]; }
    #pragma unroll
    for (int off = 32; off; off >>= 1) sum += __shfl_xor(sum, off);
    float inv = 1.f/sum;
    #pragma unroll
    for (int i = 0; i < 8; i++) {
        float a = v[i]*inv;
        __hip_bfloat16 h = __float2bfloat16(a);
        ah[(size_t)row*NS + lane + i*64] = h;
        al[(size_t)row*NS + lane + i*64] = __float2bfloat16(a - __bfloat162float(h));
    }
}

// ---------------- Wc[b,t,h] = sum_s attn[b,t,s]*ctxT[b,h,s]  (fp32 out) ----------------
__global__ __launch_bounds__(256) void gemm_wc(const __hip_bfloat16* __restrict__ Ah,
                                               const __hip_bfloat16* __restrict__ Al,
                                               const __hip_bfloat16* __restrict__ ctxT,
                                               float* __restrict__ Wc) {
    int wid = blockIdx.x*4 + (threadIdx.x>>6);
    int lane = threadIdx.x & 63;
    int b  = wid >> 3;
    int n0 = (wid & 7) * 64;
    int fr = lane & 15, fq = lane >> 4;
    const __hip_bfloat16* Abh = Ah + (size_t)b*NT_*NS;
    const __hip_bfloat16* Abl = Al + (size_t)b*NT_*NS;
    const __hip_bfloat16* Bb  = ctxT + (size_t)b*NH*NS;
    f32x4 acc[4][4] = {};
    for (int kk = 0; kk < NS; kk += 32) {
        short8 ah[4], al[4], bb[4];
        #pragma unroll
        for (int i = 0; i < 4; i++) {
            ah[i] = ld8b(Abh + (size_t)(i*16+fr)*NS + kk + fq*8);
            al[i] = ld8b(Abl + (size_t)(i*16+fr)*NS + kk + fq*8);
        }
        #pragma unroll
        for (int j = 0; j < 4; j++) bb[j] = ld8b(Bb + (size_t)(n0+j*16+fr)*NS + kk + fq*8);
        #pragma unroll
        for (int i = 0; i < 4; i++)
            #pragma unroll
            for (int j = 0; j < 4; j++) {
                acc[i][j] = __builtin_amdgcn_mfma_f32_16x16x32_bf16(ah[i], bb[j], acc[i][j], 0,0,0);
                acc[i][j] = __builtin_amdgcn_mfma_f32_16x16x32_bf16(al[i], bb[j], acc[i][j], 0,0,0);
            }
    }
    #pragma unroll
    for (int i = 0; i < 4; i++)
      #pragma unroll
      for (int j = 0; j < 4; j++)
        #pragma unroll
        for (int r = 0; r < 4; r++) {
            int t = i*16 + fq*4 + r;
            int h = n0 + j*16 + fr;
            Wc[((size_t)b*NT_ + t)*NH + h] = acc[i][j][r];
        }
}

// ---------------- out = tanh([Wc|Hf] @ W_out^T)  (M=4096,N=512,K=1024) ----------------
__global__ __launch_bounds__(256) void gemm_out(const float* __restrict__ Wc,
                                                const float* __restrict__ Hf,
                                                const __hip_bfloat16* __restrict__ Wh,
                                                const __hip_bfloat16* __restrict__ Wl,
                                                float* __restrict__ out) {
    int wid = blockIdx.x*4 + (threadIdx.x>>6);
    int lane = threadIdx.x & 63;
    int m0 = (wid >> 3) * 64;
    int n0 = (wid & 7) * 64;
    int fr = lane & 15, fq = lane >> 4;
    f32x4 acc[4][4] = {};
    #pragma unroll 1
    for (int half = 0; half < 2; half++) {
        const float* Am = half ? Hf : Wc;
        int koff = half ? NH : 0;
        for (int kk = 0; kk < NH; kk += 32) {
            short8 ah[4], al[4], bh[4], bl[4];
            #pragma unroll
            for (int i = 0; i < 4; i++) ld8f2(Am + (size_t)(m0+i*16+fr)*NH + kk + fq*8, ah[i], al[i]);
            #pragma unroll
            for (int j = 0; j < 4; j++) {
                bh[j] = ld8b(Wh + (size_t)(n0+j*16+fr)*H2 + koff + kk + fq*8);
                bl[j] = ld8b(Wl + (size_t)(n0+j*16+fr)*H2 + koff + kk + fq*8);
            }
            #pragma unroll
            for (int i = 0; i < 4; i++)
                #pragma unroll
                for (int j = 0; j < 4; j++) {
                    acc[i][j] = __builtin_amdgcn_mfma_f32_16x16x32_bf16(ah[i], bh[j], acc[i][j], 0,0,0);
                    acc[i][j] = __builtin_amdgcn_mfma_f32_16x16x32_bf16(ah[i], bl[j], acc[i][j], 0,0,0);
                    acc[i][j] = __builtin_amdgcn_mfma_f32_16x16x32_bf16(al[i], bh[j], acc[i][j], 0,0,0);
                }
        }
    }
    #pragma unroll
    for (int i = 0; i < 4; i++)
      #pragma unroll
      for (int j = 0; j < 4; j++)
        #pragma unroll
        for (int r = 0; r < 4; r++) {
            int m = m0 + i*16 + fq*4 + r;
            int n = n0 + j*16 + fr;
            out[(size_t)m*NH + n] = ftanh(acc[i][j][r]);
        }
}

// ---------------- workspace layout (bytes), total 94,371,840 (proven available) ----------------
// XW fp32 (B,T,4H)        @ 0            33,554,432  [live: gemm_xw -> recurrence]
//   scores fp32 (B,T,S)   @ 0             8,388,608  [post-recurrence overlay]
//   attn_hi bf16 (B,T,S)  @ 8,388,608     4,194,304
//   attn_lo bf16 (B,T,S)  @ 12,582,912    4,194,304
// Hf fp32 (B,T,H)         @ 33,554,432    8,388,608
// Wc fp32 (B,T,H)         @ 41,943,040    8,388,608
// Wih_hi / Wih_lo         @ 50,331,648 / 52,428,800
// Whh_hi / Whh_lo         @ 54,525,952 / 56,623,104
// Wout_hi / Wout_lo       @ 58,720,256 / 59,768,832
// ctxT bf16 (B,H,S)       @ 60,817,408   33,554,432  [written AFTER recurrence]
//   hs_h bf16 (65,B,H)    @ 60,817,408    4,259,840  [recurrence-only overlay]
//   hs_l bf16 (65,B,H)    @ 65,077,248    4,259,840
//   barrier u32           @ 69,337,088            4

extern "C" void kernel_launch(void* const* d_in, const int* in_sizes, int n_in,
                              void* d_out, int out_size, void* d_ws, size_t ws_size,
                              hipStream_t stream) {
    const float* input = (const float*)d_in[0];
    const float* h0    = (const float*)d_in[1];
    const float* c0    = (const float*)d_in[2];
    const float* ctx   = (const float*)d_in[3];
    const float* W_ih  = (const float*)d_in[4];
    const float* b_ih  = (const float*)d_in[5];
    const float* W_hh  = (const float*)d_in[6];
    const float* b_hh  = (const float*)d_in[7];
    const float* W_out = (const float*)d_in[8];
    float* out = (float*)d_out;

    if (ws_size < 94371840u) return;  // fail loudly (d_out stays poisoned)

    char* ws = (char*)d_ws;
    float*          XW     = (float*)(ws + 0);
    float*          scores = (float*)(ws + 0);
    __hip_bfloat16* attn_h = (__hip_bfloat16*)(ws + 8388608);
    __hip_bfloat16* attn_l = (__hip_bfloat16*)(ws + 12582912);
    float*          Hf     = (float*)(ws + 33554432);
    float*          Wc     = (float*)(ws + 41943040);
    __hip_bfloat16* Wih_h  = (__hip_bfloat16*)(ws + 50331648);
    __hip_bfloat16* Wih_l  = (__hip_bfloat16*)(ws + 52428800);
    __hip_bfloat16* Whh_h  = (__hip_bfloat16*)(ws + 54525952);
    __hip_bfloat16* Whh_l  = (__hip_bfloat16*)(ws + 56623104);
    __hip_bfloat16* Wout_h = (__hip_bfloat16*)(ws + 58720256);
    __hip_bfloat16* Wout_l = (__hip_bfloat16*)(ws + 59768832);
    __hip_bfloat16* ctxT   = (__hip_bfloat16*)(ws + 60817408);
    __hip_bfloat16* hs_h   = (__hip_bfloat16*)(ws + 60817408);
    __hip_bfloat16* hs_l   = (__hip_bfloat16*)(ws + 65077248);
    unsigned*       bar    = (unsigned*)(ws + 69337088);

    conv_split<<<2048, 256, 0, stream>>>(W_ih, Wih_h, Wih_l, G4*NI);
    conv_split<<<2048, 256, 0, stream>>>(W_hh, Whh_h, Whh_l, G4*NH);
    conv_split<<<1024, 256, 0, stream>>>(W_out, Wout_h, Wout_l, NH*H2);
    hseq0_init<<<128, 256, 0, stream>>>(h0, hs_h, hs_l, bar);
    gemm_xw<<<512, 256, 0, stream>>>(input, Wih_h, Wih_l, b_ih, b_hh, XW);

    float* hT = out + (size_t)BT*NH;
    float* cT = hT + NB*NH;
    lstm_persist<<<RBLK, 256, 0, stream>>>(c0, Whh_h, Whh_l, XW, hs_h, hs_l, Hf, hT, cT, bar);

    transpose_ctx<<<dim3(8,8,64), 256, 0, stream>>>(ctx, ctxT);
    gemm_scores<<<128, 256, 0, stream>>>(Hf, ctx, scores);
    softmax_rows<<<1024, 256, 0, stream>>>(scores, attn_h, attn_l);
    gemm_wc<<<128, 256, 0, stream>>>(attn_h, attn_l, ctxT, Wc);
    gemm_out<<<128, 256, 0, stream>>>(Wc, Hf, Wout_h, Wout_l, out);
}

// Round 5
// 658.302 us; speedup vs baseline: 3.0565x; 1.0704x over previous
//
#include <hip/hip_runtime.h>
#include <hip/hip_bf16.h>

// Problem constants
#define NB 64      // batch
#define NT_ 64     // time steps
#define NS 512     // source positions
#define NI 512     // input dim
#define NH 512     // hidden
#define G4 2048    // 4*H
#define H2 1024    // 2*H
#define BT (NB*NT_)
#define RBLK 64    // persistent-kernel blocks
#define CPB 8      // cells per block

typedef __attribute__((ext_vector_type(8))) short short8;   // 8 bf16 (4 VGPRs)
typedef __attribute__((ext_vector_type(4))) float f32x4;    // MFMA accumulator

__device__ __forceinline__ short f2bs(float f) {
    __hip_bfloat16 h = __float2bfloat16(f);
    return *reinterpret_cast<short*>(&h);
}
__device__ __forceinline__ float bs2f(short s) {
    unsigned int u = ((unsigned int)(unsigned short)s) << 16;
    union { unsigned int u; float f; } c; c.u = u; return c.f;
}
__device__ __forceinline__ short8 ld8b(const __hip_bfloat16* p) {
    return *reinterpret_cast<const short8*>(p);
}
// load 8 fp32, produce hi & lo bf16 fragments (x ~= hi + lo, rel err ~2^-16)
__device__ __forceinline__ void ld8f2(const float* p, short8& hi, short8& lo) {
    float4 a = *reinterpret_cast<const float4*>(p);
    float4 b = *reinterpret_cast<const float4*>(p + 4);
    float v[8] = {a.x,a.y,a.z,a.w,b.x,b.y,b.z,b.w};
    #pragma unroll
    for (int i = 0; i < 8; i++) {
        short h = f2bs(v[i]);
        hi[i] = h;
        lo[i] = f2bs(v[i] - bs2f(h));
    }
}
__device__ __forceinline__ float fsigm(float x){ return 1.f/(1.f + __expf(-x)); }
__device__ __forceinline__ float ftanh(float x){ float e = __expf(2.f*x); return 1.f - 2.f/(e + 1.f); }

// ---------------- conversions ----------------
__global__ __launch_bounds__(256) void conv_split(const float* __restrict__ s,
                                                  __hip_bfloat16* __restrict__ hi,
                                                  __hip_bfloat16* __restrict__ lo, int n) {
    for (int i = blockIdx.x*256 + threadIdx.x; i < n; i += gridDim.x*256) {
        float x = s[i];
        __hip_bfloat16 h = __float2bfloat16(x);
        hi[i] = h;
        lo[i] = __float2bfloat16(x - __bfloat162float(h));
    }
}

// h0 -> hs slot 0 (hi/lo); zero the 64 barrier flags (128B-strided, re-zeroed per call)
__global__ __launch_bounds__(256) void hseq0_init(const float* __restrict__ h0,
                                                  __hip_bfloat16* __restrict__ hs_h,
                                                  __hip_bfloat16* __restrict__ hs_l,
                                                  unsigned* __restrict__ flags) {
    int i = blockIdx.x*256 + threadIdx.x;
    if (i < RBLK*32) flags[i] = 0u;
    if (i < NB*NH) {
        float x = h0[i];
        __hip_bfloat16 h = __float2bfloat16(x);
        hs_h[i] = h;
        hs_l[i] = __float2bfloat16(x - __bfloat162float(h));
    }
}

// ctxT[b][h][s] = bf16(ctx[s][b][h])  — for the wc GEMM (dot over s)
__global__ __launch_bounds__(256) void transpose_ctx(const float* __restrict__ ctx,
                                                     __hip_bfloat16* __restrict__ ctxT) {
    __shared__ float tile[64][65];
    int s0 = blockIdx.x*64, h0 = blockIdx.y*64, b = blockIdx.z;
    int tx = threadIdx.x & 63, ty = threadIdx.x >> 6;
    for (int i = 0; i < 16; i++) {
        int s = i*4 + ty;
        tile[s][tx] = ctx[(size_t)(s0+s)*NB*NH + (size_t)b*NH + h0 + tx];
    }
    __syncthreads();
    for (int i = 0; i < 16; i++) {
        int h = i*4 + ty;
        ctxT[(size_t)b*NH*NS + (size_t)(h0+h)*NS + s0 + tx] = __float2bfloat16(tile[tx][h]);
    }
}

// ---------------- XW = input @ W_ih^T + b_ih + b_hh  (M=4096,N=2048,K=512) ----------------
__global__ __launch_bounds__(256) void gemm_xw(const float* __restrict__ X,
                                               const __hip_bfloat16* __restrict__ Wh,
                                               const __hip_bfloat16* __restrict__ Wl,
                                               const float* __restrict__ b_ih,
                                               const float* __restrict__ b_hh,
                                               float* __restrict__ XW) {
    int wid = blockIdx.x*4 + (threadIdx.x>>6);
    int lane = threadIdx.x & 63;
    int m0 = (wid >> 5) * 64;
    int n0 = (wid & 31) * 64;
    int fr = lane & 15, fq = lane >> 4;
    f32x4 acc[4][4] = {};
    for (int kk = 0; kk < NI; kk += 32) {
        short8 ah[4], al[4], bh[4], bl[4];
        #pragma unroll
        for (int i = 0; i < 4; i++) ld8f2(X + (size_t)(m0+i*16+fr)*NI + kk + fq*8, ah[i], al[i]);
        #pragma unroll
        for (int j = 0; j < 4; j++) {
            bh[j] = ld8b(Wh + (size_t)(n0+j*16+fr)*NI + kk + fq*8);
            bl[j] = ld8b(Wl + (size_t)(n0+j*16+fr)*NI + kk + fq*8);
        }
        #pragma unroll
        for (int i = 0; i < 4; i++)
            #pragma unroll
            for (int j = 0; j < 4; j++) {
                acc[i][j] = __builtin_amdgcn_mfma_f32_16x16x32_bf16(ah[i], bh[j], acc[i][j], 0,0,0);
                acc[i][j] = __builtin_amdgcn_mfma_f32_16x16x32_bf16(ah[i], bl[j], acc[i][j], 0,0,0);
                acc[i][j] = __builtin_amdgcn_mfma_f32_16x16x32_bf16(al[i], bh[j], acc[i][j], 0,0,0);
            }
    }
    #pragma unroll
    for (int i = 0; i < 4; i++)
      #pragma unroll
      for (int j = 0; j < 4; j++)
        #pragma unroll
        for (int r = 0; r < 4; r++) {
            int m = m0 + i*16 + fq*4 + r;
            int n = n0 + j*16 + fr;
            XW[(size_t)m*G4 + n] = acc[i][j][r] + b_ih[n] + b_hh[n];
        }
}

// ---------------- persistent LSTM recurrence: all 64 steps in one kernel ----------------
// 64 blocks x 256 threads. Block bi owns cells [bi*8, bi*8+8) -> 32 gate columns.
// Whh slice (hi+lo) in LDS (XOR-swizzled); c-state in registers.
// Cross-XCD h exchange WITHOUT cache fences (validated r4):
//   - h stores: device-scope relaxed atomic u32 (write-through to coherence point)
//   - h loads plain (time-series addresses -> never stale in a reader L2)
//   - barrier: DISTRIBUTED flags, one per block at 128B stride. Arrival = one
//     relaxed agent store (no RMW contention); wait = wave 0 polls all 64 flags
//     with 64 parallel lanes (one L3 round per iteration).
//   - XW for step t+1 prefetched into registers during the poll window.
__global__ __launch_bounds__(256, 1) void lstm_persist(
    const float* __restrict__ c0,
    const __hip_bfloat16* __restrict__ Whh_h,
    const __hip_bfloat16* __restrict__ Whh_l,
    const float* __restrict__ XW,
    __hip_bfloat16* __restrict__ hs_h,   // (65,B,H) bf16 time-series
    __hip_bfloat16* __restrict__ hs_l,
    float* __restrict__ hT, float* __restrict__ cT,
    unsigned* __restrict__ flags)
{
    __shared__ __hip_bfloat16 Wh[32*512];   // 32KB, swizzled
    __shared__ __hip_bfloat16 Wl[32*512];   // 32KB
    __shared__ float gl[4][32][33];         // per-wave partial gates (16.9KB)
    int tid = threadIdx.x, bi = blockIdx.x;
    int lane = tid & 63, w = tid >> 6;
    int fr = lane & 15, fq = lane >> 4;

    // --- stage Whh slice into LDS (rows jl: gate g=jl>>3, cell bi*8+(jl&7)) ---
    {
        int jl = tid >> 3, ck8 = tid & 7;
        int grow = (jl >> 3) * NH + bi * CPB + (jl & 7);
        const short8* srcH = (const short8*)(Whh_h + (size_t)grow * NH);
        const short8* srcL = (const short8*)(Whh_l + (size_t)grow * NH);
        #pragma unroll
        for (int cc = 0; cc < 8; cc++) {
            int ck = ck8 * 8 + cc;                       // 16B chunk 0..63
            int sw = (ck * 16) ^ ((jl & 7) << 4);
            *(short8*)((char*)Wh + jl * 1024 + sw) = srcH[ck];
            *(short8*)((char*)Wl + jl * 1024 + sw) = srcL[ck];
        }
    }
    // --- c-state in registers: thread -> (batch eb, cells ec0..ec0+1) ---
    int eb  = tid >> 2;
    int ec0 = (tid & 3) * 2;
    int ebl = eb & 31, mhalf = eb >> 5;
    float creg[2];
    creg[0] = c0[eb * NH + bi*CPB + ec0];
    creg[1] = c0[eb * NH + bi*CPB + ec0 + 1];
    // XW for t=0
    float xw[8];
    #pragma unroll
    for (int g = 0; g < 4; g++)
      #pragma unroll
      for (int u = 0; u < 2; u++)
        xw[g*2+u] = XW[(size_t)eb*NT_*G4 + g*NH + bi*CPB + ec0 + u];
    __syncthreads();

    int m0 = (w & 1) * 32;      // M-half (batch rows)
    int kbase = (w >> 1) * 256; // K-half

    for (int t = 0; t < NT_; t++) {
        const __hip_bfloat16* Ah = hs_h + (size_t)t * NB * NH;
        const __hip_bfloat16* Al = hs_l + (size_t)t * NB * NH;

        f32x4 acc[2][2] = {};
        #pragma unroll
        for (int kk = 0; kk < 256; kk += 32) {
            short8 a_h[2], a_l[2], b_h[2], b_l[2];
            #pragma unroll
            for (int i = 0; i < 2; i++) {
                size_t off = (size_t)(m0 + i*16 + fr) * NH + kbase + kk + fq*8;
                a_h[i] = ld8b(Ah + off);
                a_l[i] = ld8b(Al + off);
            }
            #pragma unroll
            for (int j = 0; j < 2; j++) {
                int jl = j*16 + fr;
                int byt = jl*1024 + ((((kbase + kk + fq*8)*2)) ^ ((jl & 7) << 4));
                b_h[j] = *(const short8*)((const char*)Wh + byt);
                b_l[j] = *(const short8*)((const char*)Wl + byt);
            }
            #pragma unroll
            for (int i = 0; i < 2; i++)
                #pragma unroll
                for (int j = 0; j < 2; j++) {
                    acc[i][j] = __builtin_amdgcn_mfma_f32_16x16x32_bf16(a_h[i], b_h[j], acc[i][j], 0,0,0);
                    acc[i][j] = __builtin_amdgcn_mfma_f32_16x16x32_bf16(a_h[i], b_l[j], acc[i][j], 0,0,0);
                    acc[i][j] = __builtin_amdgcn_mfma_f32_16x16x32_bf16(a_l[i], b_h[j], acc[i][j], 0,0,0);
                }
        }
        // each wave writes its partial to its own gl quadrant — ONE sync
        #pragma unroll
        for (int i = 0; i < 2; i++)
          #pragma unroll
          for (int j = 0; j < 2; j++)
            #pragma unroll
            for (int r = 0; r < 4; r++)
                gl[w][i*16 + fq*4 + r][j*16 + fr] = acc[i][j][r];
        __syncthreads();

        // --- cell elementwise (2 cells/thread): sum K-halves + XW, activate ---
        float hv[2];
        #pragma unroll
        for (int u = 0; u < 2; u++) {
            int cl = ec0 + u;
            float gi = gl[mhalf][ebl][cl]      + gl[2+mhalf][ebl][cl]      + xw[u];
            float gf = gl[mhalf][ebl][8 + cl]  + gl[2+mhalf][ebl][8 + cl]  + xw[2+u];
            float gg = gl[mhalf][ebl][16 + cl] + gl[2+mhalf][ebl][16 + cl] + xw[4+u];
            float go = gl[mhalf][ebl][24 + cl] + gl[2+mhalf][ebl][24 + cl] + xw[6+u];
            float ct = fsigm(gf)*creg[u] + fsigm(gi)*ftanh(gg);
            hv[u] = fsigm(go)*ftanh(ct);
            creg[u] = ct;
        }
        int hcol = bi*CPB + ec0;
        size_t hoff = (size_t)(t+1)*NB*NH + (size_t)eb*NH + hcol;
        unsigned short h0b = (unsigned short)f2bs(hv[0]);
        unsigned short h1b = (unsigned short)f2bs(hv[1]);
        unsigned ph = (unsigned)h0b | ((unsigned)h1b << 16);
        unsigned short l0b = (unsigned short)f2bs(hv[0] - bs2f((short)h0b));
        unsigned short l1b = (unsigned short)f2bs(hv[1] - bs2f((short)h1b));
        unsigned pl = (unsigned)l0b | ((unsigned)l1b << 16);
        __hip_atomic_store((unsigned*)&hs_h[hoff], ph, __ATOMIC_RELAXED, __HIP_MEMORY_SCOPE_AGENT);
        __hip_atomic_store((unsigned*)&hs_l[hoff], pl, __ATOMIC_RELAXED, __HIP_MEMORY_SCOPE_AGENT);
        if (t == NT_-1) {
            *(float2*)&hT[(size_t)eb*NH + hcol] = make_float2(hv[0], hv[1]);
            *(float2*)&cT[(size_t)eb*NH + hcol] = make_float2(creg[0], creg[1]);
        }

        // --- distributed-flag grid barrier ---
        asm volatile("s_waitcnt vmcnt(0)" ::: "memory");   // own h stores at coherence point
        __syncthreads();                                   // whole block's stores drained
        if (tid == 0)
            __hip_atomic_store(&flags[bi*32], (unsigned)(t+1), __ATOMIC_RELAXED, __HIP_MEMORY_SCOPE_AGENT);
        // prefetch next step's XW during the wait (independent of h)
        if (t + 1 < NT_) {
            #pragma unroll
            for (int g = 0; g < 4; g++)
              #pragma unroll
              for (int u = 0; u < 2; u++)
                xw[g*2+u] = XW[((size_t)eb*NT_ + (t+1))*G4 + g*NH + bi*CPB + ec0 + u];
        }
        if (w == 0) {   // 64 lanes poll 64 flags in parallel
            unsigned target = (unsigned)(t+1);
            int guard = 0;
            while (__hip_atomic_load(&flags[lane*32], __ATOMIC_RELAXED, __HIP_MEMORY_SCOPE_AGENT) < target) {
                __builtin_amdgcn_s_sleep(1);
                if (++guard > (1<<22)) break;   // fail loud rather than hang
            }
        }
        __syncthreads();
    }
}

// ---------------- scores[b,t,s] = h[b,t,:] . ctx[s,b,:]  (A from hs hi/lo) ----------------
__global__ __launch_bounds__(256) void gemm_scores(const __hip_bfloat16* __restrict__ hs_h,
                                                   const __hip_bfloat16* __restrict__ hs_l,
                                                   const float* __restrict__ ctx,
                                                   float* __restrict__ scores) {
    int wid = blockIdx.x*4 + (threadIdx.x>>6);
    int lane = threadIdx.x & 63;
    int b  = wid >> 3;
    int n0 = (wid & 7) * 64;
    int fr = lane & 15, fq = lane >> 4;
    const __hip_bfloat16* Abh = hs_h + NB*NH + (size_t)b*NH;   // slot t+1, row stride NB*NH
    const __hip_bfloat16* Abl = hs_l + NB*NH + (size_t)b*NH;
    const float* Bb = ctx + (size_t)b*NH;
    f32x4 acc[4][4] = {};
    for (int kk = 0; kk < NH; kk += 32) {
        short8 ah[4], al[4], bh[4], bl[4];
        #pragma unroll
        for (int i = 0; i < 4; i++) {
            size_t off = (size_t)(i*16+fr)*NB*NH + kk + fq*8;
            ah[i] = ld8b(Abh + off);
            al[i] = ld8b(Abl + off);
        }
        #pragma unroll
        for (int j = 0; j < 4; j++) ld8f2(Bb + (size_t)(n0+j*16+fr)*NB*NH + kk + fq*8, bh[j], bl[j]);
        #pragma unroll
        for (int i = 0; i < 4; i++)
            #pragma unroll
            for (int j = 0; j < 4; j++) {
                acc[i][j] = __builtin_amdgcn_mfma_f32_16x16x32_bf16(ah[i], bh[j], acc[i][j], 0,0,0);
                acc[i][j] = __builtin_amdgcn_mfma_f32_16x16x32_bf16(ah[i], bl[j], acc[i][j], 0,0,0);
                acc[i][j] = __builtin_amdgcn_mfma_f32_16x16x32_bf16(al[i], bh[j], acc[i][j], 0,0,0);
            }
    }
    #pragma unroll
    for (int i = 0; i < 4; i++)
      #pragma unroll
      for (int j = 0; j < 4; j++)
        #pragma unroll
        for (int r = 0; r < 4; r++) {
            int t = i*16 + fq*4 + r;
            int s = n0 + j*16 + fr;
            scores[((size_t)b*NT_ + t)*NS + s] = acc[i][j][r];
        }
}

// ---------------- row softmax over S, output attn hi/lo bf16 ----------------
__global__ __launch_bounds__(256) void softmax_rows(const float* __restrict__ scores,
                                                    __hip_bfloat16* __restrict__ ah,
                                                    __hip_bfloat16* __restrict__ al) {
    int row = blockIdx.x*4 + (threadIdx.x>>6);
    int lane = threadIdx.x & 63;
    const float* r = scores + (size_t)row*NS;
    float v[8], mx = -1e30f;
    #pragma unroll
    for (int i = 0; i < 8; i++) { v[i] = r[lane + i*64]; mx = fmaxf(mx, v[i]); }
    #pragma unroll
    for (int off = 32; off; off >>= 1) mx = fmaxf(mx, __shfl_xor(mx, off));
    float sum = 0.f;
    #pragma unroll
    for (int i = 0; i < 8; i++) { v[i] = __expf(v[i]-mx); sum += v[i]; }
    #pragma unroll
    for (int off = 32; off; off >>= 1) sum += __shfl_xor(sum, off);
    float inv = 1.f/sum;
    #pragma unroll
    for (int i = 0; i < 8; i++) {
        float a = v[i]*inv;
        __hip_bfloat16 h = __float2bfloat16(a);
        ah[(size_t)row*NS + lane + i*64] = h;
        al[(size_t)row*NS + lane + i*64] = __float2bfloat16(a - __bfloat162float(h));
    }
}

// ---------------- Wc[b,t,h] = sum_s attn[b,t,s]*ctxT[b,h,s]  (fp32 out) ----------------
__global__ __launch_bounds__(256) void gemm_wc(const __hip_bfloat16* __restrict__ Ah,
                                               const __hip_bfloat16* __restrict__ Al,
                                               const __hip_bfloat16* __restrict__ ctxT,
                                               float* __restrict__ Wc) {
    int wid = blockIdx.x*4 + (threadIdx.x>>6);
    int lane = threadIdx.x & 63;
    int b  = wid >> 3;
    int n0 = (wid & 7) * 64;
    int fr = lane & 15, fq = lane >> 4;
    const __hip_bfloat16* Abh = Ah + (size_t)b*NT_*NS;
    const __hip_bfloat16* Abl = Al + (size_t)b*NT_*NS;
    const __hip_bfloat16* Bb  = ctxT + (size_t)b*NH*NS;
    f32x4 acc[4][4] = {};
    for (int kk = 0; kk < NS; kk += 32) {
        short8 ah[4], al[4], bb[4];
        #pragma unroll
        for (int i = 0; i < 4; i++) {
            ah[i] = ld8b(Abh + (size_t)(i*16+fr)*NS + kk + fq*8);
            al[i] = ld8b(Abl + (size_t)(i*16+fr)*NS + kk + fq*8);
        }
        #pragma unroll
        for (int j = 0; j < 4; j++) bb[j] = ld8b(Bb + (size_t)(n0+j*16+fr)*NS + kk + fq*8);
        #pragma unroll
        for (int i = 0; i < 4; i++)
            #pragma unroll
            for (int j = 0; j < 4; j++) {
                acc[i][j] = __builtin_amdgcn_mfma_f32_16x16x32_bf16(ah[i], bb[j], acc[i][j], 0,0,0);
                acc[i][j] = __builtin_amdgcn_mfma_f32_16x16x32_bf16(al[i], bb[j], acc[i][j], 0,0,0);
            }
    }
    #pragma unroll
    for (int i = 0; i < 4; i++)
      #pragma unroll
      for (int j = 0; j < 4; j++)
        #pragma unroll
        for (int r = 0; r < 4; r++) {
            int t = i*16 + fq*4 + r;
            int h = n0 + j*16 + fr;
            Wc[((size_t)b*NT_ + t)*NH + h] = acc[i][j][r];
        }
}

// ---------------- out = tanh([Wc|h] @ W_out^T)  (M=4096,N=512,K=1024) ----------------
__global__ __launch_bounds__(256) void gemm_out(const float* __restrict__ Wc,
                                                const __hip_bfloat16* __restrict__ hs_h,
                                                const __hip_bfloat16* __restrict__ hs_l,
                                                const __hip_bfloat16* __restrict__ Wh,
                                                const __hip_bfloat16* __restrict__ Wl,
                                                float* __restrict__ out) {
    int wid = blockIdx.x*4 + (threadIdx.x>>6);
    int lane = threadIdx.x & 63;
    int m0 = (wid >> 3) * 64;
    int n0 = (wid & 7) * 64;
    int fr = lane & 15, fq = lane >> 4;
    f32x4 acc[4][4] = {};
    // half 0: Wc (fp32, split on the fly), K cols [0,512)
    for (int kk = 0; kk < NH; kk += 32) {
        short8 ah[4], al[4], bh[4], bl[4];
        #pragma unroll
        for (int i = 0; i < 4; i++) ld8f2(Wc + (size_t)(m0+i*16+fr)*NH + kk + fq*8, ah[i], al[i]);
        #pragma unroll
        for (int j = 0; j < 4; j++) {
            bh[j] = ld8b(Wh + (size_t)(n0+j*16+fr)*H2 + kk + fq*8);
            bl[j] = ld8b(Wl + (size_t)(n0+j*16+fr)*H2 + kk + fq*8);
        }
        #pragma unroll
        for (int i = 0; i < 4; i++)
            #pragma unroll
            for (int j = 0; j < 4; j++) {
                acc[i][j] = __builtin_amdgcn_mfma_f32_16x16x32_bf16(ah[i], bh[j], acc[i][j], 0,0,0);
                acc[i][j] = __builtin_amdgcn_mfma_f32_16x16x32_bf16(ah[i], bl[j], acc[i][j], 0,0,0);
                acc[i][j] = __builtin_amdgcn_mfma_f32_16x16x32_bf16(al[i], bh[j], acc[i][j], 0,0,0);
            }
    }
    // half 1: h from hs time-series (bf16 hi/lo), K cols [512,1024)
    {
        const __hip_bfloat16* A2h = hs_h + NB*NH + (size_t)(m0>>6)*NH;  // row rloc=t -> slot t+1
        const __hip_bfloat16* A2l = hs_l + NB*NH + (size_t)(m0>>6)*NH;
        for (int kk = 0; kk < NH; kk += 32) {
            short8 ah[4], al[4], bh[4], bl[4];
            #pragma unroll
            for (int i = 0; i < 4; i++) {
                size_t off = (size_t)(i*16+fr)*NB*NH + kk + fq*8;
                ah[i] = ld8b(A2h + off);
                al[i] = ld8b(A2l + off);
            }
            #pragma unroll
            for (int j = 0; j < 4; j++) {
                bh[j] = ld8b(Wh + (size_t)(n0+j*16+fr)*H2 + NH + kk + fq*8);
                bl[j] = ld8b(Wl + (size_t)(n0+j*16+fr)*H2 + NH + kk + fq*8);
            }
            #pragma unroll
            for (int i = 0; i < 4; i++)
                #pragma unroll
                for (int j = 0; j < 4; j++) {
                    acc[i][j] = __builtin_amdgcn_mfma_f32_16x16x32_bf16(ah[i], bh[j], acc[i][j], 0,0,0);
                    acc[i][j] = __builtin_amdgcn_mfma_f32_16x16x32_bf16(ah[i], bl[j], acc[i][j], 0,0,0);
                    acc[i][j] = __builtin_amdgcn_mfma_f32_16x16x32_bf16(al[i], bh[j], acc[i][j], 0,0,0);
                }
        }
    }
    #pragma unroll
    for (int i = 0; i < 4; i++)
      #pragma unroll
      for (int j = 0; j < 4; j++)
        #pragma unroll
        for (int r = 0; r < 4; r++) {
            int m = m0 + i*16 + fq*4 + r;
            int n = n0 + j*16 + fr;
            out[(size_t)m*NH + n] = ftanh(acc[i][j][r]);
        }
}

// ---------------- workspace layout (bytes), total 94,371,840 (proven available) ----------------
// XW fp32 (B,T,4H)        @ 0            33,554,432  [live: gemm_xw -> recurrence]
//   scores fp32 (B,T,S)   @ 0             8,388,608  [post-recurrence overlay]
//   attn_hi bf16 (B,T,S)  @ 8,388,608     4,194,304
//   attn_lo bf16 (B,T,S)  @ 12,582,912    4,194,304
// (free; was Hf)          @ 33,554,432    8,388,608
// Wc fp32 (B,T,H)         @ 41,943,040    8,388,608
// Wih_hi / Wih_lo         @ 50,331,648 / 52,428,800
// Whh_hi / Whh_lo         @ 54,525,952 / 56,623,104
// Wout_hi / Wout_lo       @ 58,720,256 / 59,768,832
// ctxT bf16 (B,H,S)       @ 60,817,408   33,554,432  [written AFTER recurrence]
//   hs_h bf16 (65,B,H)    @ 60,817,408    4,259,840  [recurrence + scores/out]
//   hs_l bf16 (65,B,H)    @ 65,077,248    4,259,840
//   flags u32[64*32]      @ 69,337,088        8,192  [dead after recurrence]
// NOTE: ctxT overlaps hs/flags — but transpose_ctx runs after lstm_persist and
// gemm_wc (ctxT reader) doesn't touch hs... CAREFUL: gemm_scores/gemm_out READ hs
// after transpose_ctx writes ctxT. ctxT spans the hs region! -> move hs out.
// Corrected layout: hs_h @ 33,554,432 (old Hf region, 4.26MB), hs_l @ 37,814,272,
// flags @ 42,074,112 ... but Wc starts 41,943,040 -> overlap! Final layout below:
//   hs_h bf16 (65,B,H)    @ 33,554,432    4,259,840
//   hs_l bf16 (65,B,H)    @ 37,814,272    4,259,840
//   flags u32[64*32]      @ 42,083,328        8,192   (Wc moved)
//   Wc fp32 (B,T,H)       @ 42,091,520    8,388,608   (ends 50,480,128 < Wih_h? NO: 50,480,128 > 50,331,648)
// -> shift weight regions up by 256KB: see kernel_launch offsets (authoritative).

extern "C" void kernel_launch(void* const* d_in, const int* in_sizes, int n_in,
                              void* d_out, int out_size, void* d_ws, size_t ws_size,
                              hipStream_t stream) {
    const float* input = (const float*)d_in[0];
    const float* h0    = (const float*)d_in[1];
    const float* c0    = (const float*)d_in[2];
    const float* ctx   = (const float*)d_in[3];
    const float* W_ih  = (const float*)d_in[4];
    const float* b_ih  = (const float*)d_in[5];
    const float* W_hh  = (const float*)d_in[6];
    const float* b_hh  = (const float*)d_in[7];
    const float* W_out = (const float*)d_in[8];
    float* out = (float*)d_out;

    // authoritative offsets (bytes)
    const size_t OFF_XW     = 0;          // 33,554,432
    const size_t OFF_SCORES = 0;          //  8,388,608 (after recurrence)
    const size_t OFF_ATTN_H = 8388608;    //  4,194,304
    const size_t OFF_ATTN_L = 12582912;   //  4,194,304
    const size_t OFF_HS_H   = 33554432;   //  4,259,840 (65,B,H) — persists through tail
    const size_t OFF_HS_L   = 37814272;   //  4,259,840
    const size_t OFF_FLAGS  = 42074112;   //      8,192
    const size_t OFF_WC     = 42082304;   //  8,388,608
    const size_t OFF_WIH_H  = 50470912;   //  2,097,152
    const size_t OFF_WIH_L  = 52568064;   //  2,097,152
    const size_t OFF_WHH_H  = 54665216;   //  2,097,152
    const size_t OFF_WHH_L  = 56762368;   //  2,097,152
    const size_t OFF_WOUT_H = 58859520;   //  1,048,576
    const size_t OFF_WOUT_L = 59908096;   //  1,048,576
    const size_t OFF_CTXT   = 60956672;   // 33,554,432 -> end 94,511,104
    if (ws_size < 94511104u) return;  // fail loudly (d_out stays poisoned)

    char* ws = (char*)d_ws;
    float*          XW     = (float*)(ws + OFF_XW);
    float*          scores = (float*)(ws + OFF_SCORES);
    __hip_bfloat16* attn_h = (__hip_bfloat16*)(ws + OFF_ATTN_H);
    __hip_bfloat16* attn_l = (__hip_bfloat16*)(ws + OFF_ATTN_L);
    __hip_bfloat16* hs_h   = (__hip_bfloat16*)(ws + OFF_HS_H);
    __hip_bfloat16* hs_l   = (__hip_bfloat16*)(ws + OFF_HS_L);
    unsigned*       flags  = (unsigned*)(ws + OFF_FLAGS);
    float*          Wc     = (float*)(ws + OFF_WC);
    __hip_bfloat16* Wih_h  = (__hip_bfloat16*)(ws + OFF_WIH_H);
    __hip_bfloat16* Wih_l  = (__hip_bfloat16*)(ws + OFF_WIH_L);
    __hip_bfloat16* Whh_h  = (__hip_bfloat16*)(ws + OFF_WHH_H);
    __hip_bfloat16* Whh_l  = (__hip_bfloat16*)(ws + OFF_WHH_L);
    __hip_bfloat16* Wout_h = (__hip_bfloat16*)(ws + OFF_WOUT_H);
    __hip_bfloat16* Wout_l = (__hip_bfloat16*)(ws + OFF_WOUT_L);
    __hip_bfloat16* ctxT   = (__hip_bfloat16*)(ws + OFF_CTXT);

    conv_split<<<2048, 256, 0, stream>>>(W_ih, Wih_h, Wih_l, G4*NI);
    conv_split<<<2048, 256, 0, stream>>>(W_hh, Whh_h, Whh_l, G4*NH);
    conv_split<<<1024, 256, 0, stream>>>(W_out, Wout_h, Wout_l, NH*H2);
    hseq0_init<<<128, 256, 0, stream>>>(h0, hs_h, hs_l, flags);
    gemm_xw<<<512, 256, 0, stream>>>(input, Wih_h, Wih_l, b_ih, b_hh, XW);

    float* hT = out + (size_t)BT*NH;
    float* cT = hT + NB*NH;
    lstm_persist<<<RBLK, 256, 0, stream>>>(c0, Whh_h, Whh_l, XW, hs_h, hs_l, hT, cT, flags);

    transpose_ctx<<<dim3(8,8,64), 256, 0, stream>>>(ctx, ctxT);
    gemm_scores<<<128, 256, 0, stream>>>(hs_h, hs_l, ctx, scores);
    softmax_rows<<<1024, 256, 0, stream>>>(scores, attn_h, attn_l);
    gemm_wc<<<128, 256, 0, stream>>>(attn_h, attn_l, ctxT, Wc);
    gemm_out<<<128, 256, 0, stream>>>(Wc, hs_h, hs_l, Wout_h, Wout_l, out);
}